// Round 13
// baseline (232.632 us; speedup 1.0000x reference)
//
#include <hip/hip_runtime.h>

typedef unsigned short u16;
typedef unsigned int u32;
typedef __attribute__((ext_vector_type(4))) float f32x4;
typedef __attribute__((ext_vector_type(16))) float f32x16;
typedef __attribute__((ext_vector_type(8))) short bf16x8;

// Problem sizes (fixed): B=2, S=2048, D=2048, NH=16, NKV=4, HD=128

__device__ __forceinline__ u16 f2b(float f) {
  u32 u = __builtin_bit_cast(u32, f);
  u = (u + 0x7fffu + ((u >> 16) & 1u)) >> 16;  // RNE
  return (u16)u;
}

__device__ __forceinline__ void gload_lds16(const void* g, void* l) {
  __builtin_amdgcn_global_load_lds((const __attribute__((address_space(1))) u32*)g,
                                   (__attribute__((address_space(3))) u32*)l, 16, 0, 0);
}

// ---- cross-half (lane <-> lane^32) exchange via v_permlane32_swap_b32 (VALU pipe) ----
#if __has_builtin(__builtin_amdgcn_permlane32_swap)
#define HAS_PLS 1
__device__ __forceinline__ void pls(u32 x, u32 y, u32& rx, u32& ry) {
  auto r = __builtin_amdgcn_permlane32_swap(x, y, false, false);
  rx = (u32)r[0];
  ry = (u32)r[1];
}
#endif

__device__ __forceinline__ float xhalf_max(float v) {
#ifdef HAS_PLS
  u32 a, b;
  pls(__builtin_bit_cast(u32, v), __builtin_bit_cast(u32, v), a, b);
  return fmaxf(__builtin_bit_cast(float, a), __builtin_bit_cast(float, b));
#else
  return fmaxf(v, __shfl_xor(v, 32));
#endif
}

__device__ __forceinline__ float xhalf_sum(float v) {
#ifdef HAS_PLS
  u32 a, b;
  pls(__builtin_bit_cast(u32, v), __builtin_bit_cast(u32, v), a, b);
  return __builtin_bit_cast(float, a) + __builtin_bit_cast(float, b);
#else
  return v + __shfl_xor(v, 32);
#endif
}

// P-fragment redistribution across lane halves
__device__ __forceinline__ void xexchange(int hi, u32 a0, u32 a1, u32 a2, u32 a3, u32* o) {
#ifdef HAS_PLS
  pls(a0, a2, o[0], o[2]);
  pls(a1, a3, o[1], o[3]);
#else
  u32 xa0 = (u32)__shfl_xor((int)a0, 32), xa1 = (u32)__shfl_xor((int)a1, 32);
  u32 xa2 = (u32)__shfl_xor((int)a2, 32), xa3 = (u32)__shfl_xor((int)a3, 32);
  o[0] = hi ? xa2 : a0;
  o[1] = hi ? xa3 : a1;
  o[2] = hi ? a2 : xa0;
  o[3] = hi ? a3 : xa1;
#endif
}

// truncating bf16 pair pack (P in [0,1]; <=2^-8 rel err, cheap: 3 ops)
__device__ __forceinline__ u32 pktrunc(float lo, float hif) {
  return (__builtin_bit_cast(u32, lo) >> 16) | (__builtin_bit_cast(u32, hif) & 0xffff0000u);
}

// ---------------- fp32 -> bf16 conversion ----------------
__global__ void cvt_bf16(const float* __restrict__ src, u16* __restrict__ dst, int n) {
  int stride = gridDim.x * blockDim.x * 4;
  for (int idx = (blockIdx.x * blockDim.x + threadIdx.x) * 4; idx < n; idx += stride) {
    float4 v = *(const float4*)(src + idx);
    ushort4 o;
    o.x = f2b(v.x); o.y = f2b(v.y); o.z = f2b(v.z); o.w = f2b(v.w);
    *(ushort4*)(dst + idx) = o;
  }
}

// fused weight conversion: dst = [Wq | Wk | Wv | Wo] contiguous
__global__ void cvt_w4(const float* __restrict__ Wq, const float* __restrict__ Wk,
                       const float* __restrict__ Wv, const float* __restrict__ Wo,
                       u16* __restrict__ dst) {
  const int total = 10485760;
  int stride = gridDim.x * blockDim.x * 4;
  for (int idx = (blockIdx.x * blockDim.x + threadIdx.x) * 4; idx < total; idx += stride) {
    const float* src;
    int off;
    if (idx < 4194304) { src = Wq; off = idx; }
    else if (idx < 5242880) { src = Wk; off = idx - 4194304; }
    else if (idx < 6291456) { src = Wv; off = idx - 5242880; }
    else { src = Wo; off = idx - 6291456; }
    float4 v = *(const float4*)(src + off);
    ushort4 o;
    o.x = f2b(v.x); o.y = f2b(v.y); o.z = f2b(v.z); o.w = f2b(v.w);
    *(ushort4*)(dst + idx) = o;
  }
}

// ---------------- GEMM: C[M,N] = A[M,K] * B[N,K]^T ----------------
// OUT_MODE: 0 = bf16 row-major; 2 = fp32 row-major; 3 = fused QKV routing.
// Mode 3 writes K and V in MFMA-FRAGMENT order via LDS-staged coalesced epilogue.
//   Kf[((b*4+kvh)*64 + kvt)*8 + ck][lane = hi*32+ql][j]
//   Vf[(((b*4+kvh)*64 + kvt)*2 + ks)*4 + db][lane][j]
template<int OUT_MODE>
__global__ __launch_bounds__(256) void gemm_bt(const u16* __restrict__ A, const u16* __restrict__ B,
                                               void* __restrict__ Cout, int M, int N, int Kd,
                                               u16* __restrict__ Kout, u16* __restrict__ Vtout) {
  __shared__ u16 smem[(OUT_MODE == 3) ? 16384 : 8192];
  u16* sA = smem;
  u16* sB = smem + 4096;
  const int tid = threadIdx.x;
  const int l = tid & 63, w = tid >> 6;
  const int wr = w >> 1, wc = w & 1;
  const int g = l >> 4, c = l & 15;
  const int tm = blockIdx.y * 128, tn = blockIdx.x * 128;

  f32x4 acc[4][4] = {};

  const int r0 = tid >> 2, cc = (tid & 3) << 3;

  for (int k0 = 0; k0 < Kd; k0 += 32) {
    __syncthreads();
    {
      const u16* srcA0 = A + (size_t)(tm + r0) * Kd + k0 + cc;
      const u16* srcB0 = B + (size_t)(tn + r0) * Kd + k0 + cc;
      gload_lds16(srcA0, (char*)sA + w * 1024);
      gload_lds16(srcB0, (char*)sB + w * 1024);
      gload_lds16(srcA0 + (size_t)64 * Kd, (char*)sA + 4096 + w * 1024);
      gload_lds16(srcB0 + (size_t)64 * Kd, (char*)sB + 4096 + w * 1024);
    }
    __syncthreads();

    bf16x8 af[4], bfr[4];
#pragma unroll
    for (int m = 0; m < 4; ++m)
      af[m] = *(const bf16x8*)(sA + (wr * 64 + m * 16 + c) * 32 + g * 8);
#pragma unroll
    for (int n = 0; n < 4; ++n)
      bfr[n] = *(const bf16x8*)(sB + (wc * 64 + n * 16 + c) * 32 + g * 8);
#pragma unroll
    for (int m = 0; m < 4; ++m)
#pragma unroll
      for (int n = 0; n < 4; ++n)
        acc[m][n] = __builtin_amdgcn_mfma_f32_16x16x32_bf16(af[m], bfr[n], acc[m][n], 0, 0, 0);
  }

  if constexpr (OUT_MODE == 3) {
    if (tn >= 2048) {
      // ---- K/V fragment-order epilogue via LDS staging ----
      const bool isK = tn < 2560;
      __syncthreads();  // all MFMA LDS reads done before smem reuse
#pragma unroll
      for (int m = 0; m < 4; ++m)
#pragma unroll
        for (int n = 0; n < 4; ++n)
#pragma unroll
          for (int i = 0; i < 4; ++i) {
            int lr = wr * 64 + m * 16 + g * 4 + i;   // local row (kv position s)
            int lc = wc * 64 + n * 16 + c;           // local col (k or d)
            int off;
            if (isK)
              off = ((lr >> 5) << 12) + ((lc >> 4) << 9) + (((lc >> 3) & 1) << 8) +
                    ((lr & 31) << 3) + (lc & 7);
            else
              off = ((lr >> 5) << 12) + (((lr >> 4) & 1) << 11) + ((lc >> 5) << 9) +
                    (((lr >> 3) & 1) << 8) + ((lc & 31) << 3) + (lr & 7);
            smem[off] = f2b(acc[m][n][i]);
          }
      __syncthreads();
      const int e0 = tn - (isK ? 2048 : 2560);
      const int bb = tm >> 11;
      u16* dstbase = (isK ? Kout : Vtout) +
                     ((((size_t)(bb * 4 + (e0 >> 7)) * 64 + ((tm & 2047) >> 5))) << 12);
#pragma unroll
      for (int ps = 0; ps < 8; ++ps) {
        int idx = ps * 2048 + tid * 8;
        *(bf16x8*)(dstbase + idx) = *(const bf16x8*)(smem + idx);
      }
      return;
    }
  }

#pragma unroll
  for (int m = 0; m < 4; ++m)
#pragma unroll
    for (int n = 0; n < 4; ++n)
#pragma unroll
      for (int i = 0; i < 4; ++i) {
        int row = tm + wr * 64 + m * 16 + g * 4 + i;
        int col = tn + wc * 64 + n * 16 + c;
        float v = acc[m][n][i];
        if constexpr (OUT_MODE == 2) {
          ((float*)Cout)[(size_t)row * N + col] = v;
        } else {
          ((u16*)Cout)[(size_t)row * 2048 + col] = f2b(v);  // Q / bf16 row-major (ld 2048)
        }
      }
}

// ---------------- causal GQA flash attention: 32x32 swapped-operand, 4-way KV-split ----
// grid (64, 32), block 256 (4 waves). ONE 32-row q-subtile per block: t = 63 - bx
// (longest first, dispatcher backfill). Wave w takes kv-tiles kv = (w + 4i)*32 —
// intra-block wave imbalance <= 1 tile by construction (round 10/12's per-block pairing
// left ~33% of wave-slots idle at the merge barrier). 2-stage pairwise merge via LDS.
// K/V are MFMA-fragment-ordered: every load = 64 lanes x contiguous 16 B.
// NOTE: min-waves arg MUST be 2 — (256,4) caps VGPR at 64 and spills (round 8: 5x regression).
__global__ __launch_bounds__(256, 2) void attn_fwd(const u16* __restrict__ Q, const u16* __restrict__ Kf,
                                                   const u16* __restrict__ Vf, u16* __restrict__ AO) {
  const int l = threadIdx.x & 63, w = threadIdx.x >> 6;
  const int ql = l & 31, hi = l >> 5;
  const int bh = blockIdx.y;
  const int b = bh >> 4, h = bh & 15;
  const int kvh = h >> 2;

  __shared__ float4 mO[2][16][64];   // [slot][elem][lane]
  __shared__ float mML[2][2][64];

  const float sm = 0.08838834764831845f * 1.4426950408889634f;  // 1/sqrt(128) * log2(e)

  // fragment-ordered bases: 64 kv-tiles x 4096 u16 per (b,kvh)
  const u16* Kfb = Kf + (size_t)(b * 4 + kvh) * 64 * 4096 + l * 8;
  const u16* Vfb = Vf + (size_t)(b * 4 + kvh) * 64 * 4096 + l * 8;

  const int t = 63 - (int)blockIdx.x;
  const int q0 = t * 32;

  // Q fragments (B-operand of QK: col=q=lane&31, k = ck*16 + hi*8 + j)
  bf16x8 qf[8];
  {
    const u16* qb = Q + ((size_t)(b * 2048 + q0 + ql)) * 2048 + h * 128 + hi * 8;
#pragma unroll
    for (int ck = 0; ck < 8; ++ck) qf[ck] = *(const bf16x8*)(qb + ck * 16);
  }

  f32x16 acc[4] = {};  // O^T[d = db*32 + crow(r)][q = q0 + (lane&31)]
  float mrow = -1e30f, lrow = 0.f;

  bf16x8 kfa[8], kfb[8];

#define LOADK(KF, KV0)                                                        \
  do {                                                                        \
    const u16* kb_ = Kfb + (size_t)((KV0) >> 5) * 4096;                       \
    _Pragma("unroll") for (int ck = 0; ck < 8; ++ck)                          \
        KF[ck] = *(const bf16x8*)(kb_ + ck * 512);                            \
  } while (0)

#define COMPUTE(KF, KV0)                                                      \
  do {                                                                        \
    bf16x8 vtf[2][4];                                                         \
    {                                                                         \
      const u16* vb_ = Vfb + (size_t)((KV0) >> 5) * 4096;                     \
      _Pragma("unroll") for (int ks = 0; ks < 2; ++ks)                        \
      _Pragma("unroll") for (int db = 0; db < 4; ++db)                        \
          vtf[ks][db] = *(const bf16x8*)(vb_ + (ks * 4 + db) * 512);          \
    }                                                                         \
    f32x16 sacc = {};                                                         \
    __builtin_amdgcn_s_setprio(1);                                            \
    _Pragma("unroll") for (int ck = 0; ck < 8; ++ck)                          \
        sacc = __builtin_amdgcn_mfma_f32_32x32x16_bf16(KF[ck], qf[ck], sacc, 0, 0, 0); \
    __builtin_amdgcn_s_setprio(0);                                            \
    if ((KV0) == q0) { /* diagonal: mask kv > q */                            \
      _Pragma("unroll") for (int r = 0; r < 16; ++r) {                        \
        int crow = (r & 3) + 8 * (r >> 2) + 4 * hi;                           \
        if (crow > ql) sacc[r] = -1e30f;                                      \
      }                                                                       \
    }                                                                         \
    float t0 = fmaxf(sacc[0], sacc[1]), t1 = fmaxf(sacc[2], sacc[3]);         \
    float t2 = fmaxf(sacc[4], sacc[5]), t3 = fmaxf(sacc[6], sacc[7]);         \
    float t4 = fmaxf(sacc[8], sacc[9]), t5 = fmaxf(sacc[10], sacc[11]);       \
    float t6 = fmaxf(sacc[12], sacc[13]), t7 = fmaxf(sacc[14], sacc[15]);     \
    float mx = fmaxf(fmaxf(fmaxf(t0, t1), fmaxf(t2, t3)),                     \
                     fmaxf(fmaxf(t4, t5), fmaxf(t6, t7)));                    \
    mx = xhalf_max(mx);                                                       \
    float p[16];                                                              \
    _Pragma("unroll") for (int r = 0; r < 16; ++r)                            \
        p[r] = exp2f((sacc[r] - mrow) * sm);                                  \
    if (!__all((mx - mrow) * sm <= 8.0f)) { /* T13 defer-max */               \
      float mnew = fmaxf(mrow, mx);                                           \
      float rs = exp2f((mrow - mnew) * sm);                                   \
      mrow = mnew;                                                            \
      lrow *= rs;                                                             \
      _Pragma("unroll") for (int db = 0; db < 4; ++db)                        \
      _Pragma("unroll") for (int r = 0; r < 16; ++r) acc[db][r] *= rs;        \
      _Pragma("unroll") for (int r = 0; r < 16; ++r)                          \
          p[r] = exp2f((sacc[r] - mrow) * sm);                                \
    }                                                                         \
    float s0 = p[0] + p[1], s1 = p[2] + p[3], s2 = p[4] + p[5], s3 = p[6] + p[7]; \
    float s4 = p[8] + p[9], s5 = p[10] + p[11], s6 = p[12] + p[13], s7 = p[14] + p[15]; \
    float psum = ((s0 + s1) + (s2 + s3)) + ((s4 + s5) + (s6 + s7));           \
    lrow += xhalf_sum(psum);                                                  \
    u32 a0 = pktrunc(p[0], p[1]), a1 = pktrunc(p[2], p[3]);                   \
    u32 a2 = pktrunc(p[4], p[5]), a3 = pktrunc(p[6], p[7]);                   \
    u32 b0 = pktrunc(p[8], p[9]), b1 = pktrunc(p[10], p[11]);                 \
    u32 b2 = pktrunc(p[12], p[13]), b3 = pktrunc(p[14], p[15]);               \
    union { bf16x8 v; u32 u[4]; } pa0, pa1;                                   \
    xexchange(hi, a0, a1, a2, a3, pa0.u);                                     \
    xexchange(hi, b0, b1, b2, b3, pa1.u);                                     \
    __builtin_amdgcn_s_setprio(1);                                            \
    _Pragma("unroll") for (int db = 0; db < 4; ++db) {                        \
      acc[db] = __builtin_amdgcn_mfma_f32_32x32x16_bf16(vtf[0][db], pa0.v, acc[db], 0, 0, 0); \
      acc[db] = __builtin_amdgcn_mfma_f32_32x32x16_bf16(vtf[1][db], pa1.v, acc[db], 0, 0, 0); \
    }                                                                         \
    __builtin_amdgcn_s_setprio(0);                                            \
  } while (0)

  // kv loop: wave w takes tiles kv0 = w*32, (w+4)*32, ... while kv0 <= q0 (K dbuf)
  int kv0 = w * 32;
  if (kv0 <= q0) {
    LOADK(kfa, kv0);
    while (true) {
      bool more = kv0 + 128 <= q0;
      if (more) LOADK(kfb, kv0 + 128);
      COMPUTE(kfa, kv0);
      if (!more) break;
      kv0 += 128;
      more = kv0 + 128 <= q0;
      if (more) LOADK(kfa, kv0 + 128);
      COMPUTE(kfb, kv0);
      if (!more) break;
      kv0 += 128;
    }
  }
#undef LOADK
#undef COMPUTE

  // ---- 2-stage pairwise merge: (0<-2, 1<-3), then (0<-1); wave 0 stores ----
#define PUBLISH(SLOT)                                                         \
  do {                                                                        \
    _Pragma("unroll") for (int db = 0; db < 4; ++db)                          \
    _Pragma("unroll") for (int rq = 0; rq < 4; ++rq) {                        \
      float4 v;                                                               \
      v.x = acc[db][rq * 4 + 0];                                              \
      v.y = acc[db][rq * 4 + 1];                                              \
      v.z = acc[db][rq * 4 + 2];                                              \
      v.w = acc[db][rq * 4 + 3];                                              \
      mO[SLOT][db * 4 + rq][l] = v;                                           \
    }                                                                         \
    mML[SLOT][0][l] = mrow;                                                   \
    mML[SLOT][1][l] = lrow;                                                   \
  } while (0)

#define MERGE(SLOT)                                                           \
  do {                                                                        \
    float m1 = mML[SLOT][0][l], l1 = mML[SLOT][1][l];                         \
    float mnew = fmaxf(mrow, m1);                                             \
    float f0 = exp2f((mrow - mnew) * sm);                                     \
    float f1 = exp2f((m1 - mnew) * sm);                                       \
    mrow = mnew;                                                              \
    lrow = lrow * f0 + l1 * f1;                                               \
    _Pragma("unroll") for (int db = 0; db < 4; ++db)                          \
    _Pragma("unroll") for (int rq = 0; rq < 4; ++rq) {                        \
      float4 o1 = mO[SLOT][db * 4 + rq][l];                                   \
      acc[db][rq * 4 + 0] = acc[db][rq * 4 + 0] * f0 + o1.x * f1;             \
      acc[db][rq * 4 + 1] = acc[db][rq * 4 + 1] * f0 + o1.y * f1;             \
      acc[db][rq * 4 + 2] = acc[db][rq * 4 + 2] * f0 + o1.z * f1;             \
      acc[db][rq * 4 + 3] = acc[db][rq * 4 + 3] * f0 + o1.w * f1;             \
    }                                                                         \
  } while (0)

  if (w >= 2) PUBLISH(w - 2);
  __syncthreads();
  if (w < 2) MERGE(w);
  __syncthreads();
  if (w == 1) PUBLISH(0);
  __syncthreads();
  if (w == 0) {
    MERGE(0);
    float inv = 1.0f / lrow;
    u16* ob = AO + (size_t)(b * 2048 + q0 + ql) * 2048 + h * 128 + hi * 4;
#pragma unroll
    for (int db = 0; db < 4; ++db)
#pragma unroll
      for (int rq = 0; rq < 4; ++rq) {
        ushort4 o;
        o.x = f2b(acc[db][rq * 4 + 0] * inv);
        o.y = f2b(acc[db][rq * 4 + 1] * inv);
        o.z = f2b(acc[db][rq * 4 + 2] * inv);
        o.w = f2b(acc[db][rq * 4 + 3] * inv);
        *(ushort4*)(ob + db * 32 + rq * 8) = o;
      }
  }
#undef PUBLISH
#undef MERGE
}

// ---------------- host ----------------
extern "C" void kernel_launch(void* const* d_in, const int* in_sizes, int n_in,
                              void* d_out, int out_size, void* d_ws, size_t ws_size,
                              hipStream_t stream) {
  const float* X = (const float*)d_in[0];
  const float* Wq = (const float*)d_in[1];
  const float* Wk = (const float*)d_in[2];
  const float* Wv = (const float*)d_in[3];
  const float* Wo = (const float*)d_in[4];

  u16* ws = (u16*)d_ws;
  const size_t nX = 8388608;   // 2*2048*2048
  const size_t nWq = 4194304;  // 2048*2048
  const size_t nWk = 1048576;  // 512*2048
  u16* Xb = ws;
  u16* Wqb = Xb + nX;          // [Wq|Wk|Wv] contiguous = fused 3072x2048 weight
  u16* Wkb = Wqb + nWq;
  u16* Wvb = Wkb + nWk;
  u16* Wob = Wvb + nWk;
  u16* Qb = Wob + nWq;
  u16* Kfb = Qb + nX;          // K in fragment order (2M u16)
  u16* Vfb = Kfb + 2097152;    // V in fragment order (2M u16)
  u16* AOb = Vfb + 2097152;
  if (ws_size < (size_t)(39845888) * 2) return;

  cvt_bf16<<<2048, 256, 0, stream>>>(X, Xb, (int)nX);
  cvt_w4<<<2048, 256, 0, stream>>>(Wq, Wk, Wv, Wo, Wqb);

  // fused QKV projection: C[4096][3072] routed to Q / K-frag / V-frag
  gemm_bt<3><<<dim3(24, 32), 256, 0, stream>>>(Xb, Wqb, Qb, 4096, 3072, 2048, Kfb, Vfb);

  attn_fwd<<<dim3(64, 32), 256, 0, stream>>>(Qb, Kfb, Vfb, AOb);

  // output projection -> fp32 d_out
  gemm_bt<2><<<dim3(16, 32), 256, 0, stream>>>(AOb, Wob, d_out, 4096, 2048, 2048, nullptr, nullptr);
}

// Round 14
// 216.448 us; speedup vs baseline: 1.0748x; 1.0748x over previous
//
#include <hip/hip_runtime.h>

typedef unsigned short u16;
typedef unsigned int u32;
typedef __attribute__((ext_vector_type(4))) float f32x4;
typedef __attribute__((ext_vector_type(16))) float f32x16;
typedef __attribute__((ext_vector_type(8))) short bf16x8;

// Problem sizes (fixed): B=2, S=2048, D=2048, NH=16, NKV=4, HD=128

__device__ __forceinline__ u16 f2b(float f) {
  u32 u = __builtin_bit_cast(u32, f);
  u = (u + 0x7fffu + ((u >> 16) & 1u)) >> 16;  // RNE
  return (u16)u;
}

__device__ __forceinline__ void gload_lds16(const void* g, void* l) {
  __builtin_amdgcn_global_load_lds((const __attribute__((address_space(1))) u32*)g,
                                   (__attribute__((address_space(3))) u32*)l, 16, 0, 0);
}

// ---- cross-half (lane <-> lane^32) exchange via v_permlane32_swap_b32 (VALU pipe) ----
#if __has_builtin(__builtin_amdgcn_permlane32_swap)
#define HAS_PLS 1
__device__ __forceinline__ void pls(u32 x, u32 y, u32& rx, u32& ry) {
  auto r = __builtin_amdgcn_permlane32_swap(x, y, false, false);
  rx = (u32)r[0];
  ry = (u32)r[1];
}
#endif

__device__ __forceinline__ float xhalf_max(float v) {
#ifdef HAS_PLS
  u32 a, b;
  pls(__builtin_bit_cast(u32, v), __builtin_bit_cast(u32, v), a, b);
  return fmaxf(__builtin_bit_cast(float, a), __builtin_bit_cast(float, b));
#else
  return fmaxf(v, __shfl_xor(v, 32));
#endif
}

__device__ __forceinline__ float xhalf_sum(float v) {
#ifdef HAS_PLS
  u32 a, b;
  pls(__builtin_bit_cast(u32, v), __builtin_bit_cast(u32, v), a, b);
  return __builtin_bit_cast(float, a) + __builtin_bit_cast(float, b);
#else
  return v + __shfl_xor(v, 32);
#endif
}

// P-fragment redistribution across lane halves
__device__ __forceinline__ void xexchange(int hi, u32 a0, u32 a1, u32 a2, u32 a3, u32* o) {
#ifdef HAS_PLS
  pls(a0, a2, o[0], o[2]);
  pls(a1, a3, o[1], o[3]);
#else
  u32 xa0 = (u32)__shfl_xor((int)a0, 32), xa1 = (u32)__shfl_xor((int)a1, 32);
  u32 xa2 = (u32)__shfl_xor((int)a2, 32), xa3 = (u32)__shfl_xor((int)a3, 32);
  o[0] = hi ? xa2 : a0;
  o[1] = hi ? xa3 : a1;
  o[2] = hi ? a2 : xa0;
  o[3] = hi ? a3 : xa1;
#endif
}

// truncating bf16 pair pack (P in [0,1]; <=2^-8 rel err, cheap: 3 ops)
__device__ __forceinline__ u32 pktrunc(float lo, float hif) {
  return (__builtin_bit_cast(u32, lo) >> 16) | (__builtin_bit_cast(u32, hif) & 0xffff0000u);
}

// ---------------- fp32 -> bf16 conversion ----------------
__global__ void cvt_bf16(const float* __restrict__ src, u16* __restrict__ dst, int n) {
  int stride = gridDim.x * blockDim.x * 4;
  for (int idx = (blockIdx.x * blockDim.x + threadIdx.x) * 4; idx < n; idx += stride) {
    float4 v = *(const float4*)(src + idx);
    ushort4 o;
    o.x = f2b(v.x); o.y = f2b(v.y); o.z = f2b(v.z); o.w = f2b(v.w);
    *(ushort4*)(dst + idx) = o;
  }
}

// fused weight conversion: dst = [Wq | Wk | Wv | Wo] contiguous
__global__ void cvt_w4(const float* __restrict__ Wq, const float* __restrict__ Wk,
                       const float* __restrict__ Wv, const float* __restrict__ Wo,
                       u16* __restrict__ dst) {
  const int total = 10485760;
  int stride = gridDim.x * blockDim.x * 4;
  for (int idx = (blockIdx.x * blockDim.x + threadIdx.x) * 4; idx < total; idx += stride) {
    const float* src;
    int off;
    if (idx < 4194304) { src = Wq; off = idx; }
    else if (idx < 5242880) { src = Wk; off = idx - 4194304; }
    else if (idx < 6291456) { src = Wv; off = idx - 5242880; }
    else { src = Wo; off = idx - 6291456; }
    float4 v = *(const float4*)(src + off);
    ushort4 o;
    o.x = f2b(v.x); o.y = f2b(v.y); o.z = f2b(v.z); o.w = f2b(v.w);
    *(ushort4*)(dst + idx) = o;
  }
}

// ---------------- GEMM: C[M,N] = A[M,K] * B[N,K]^T ----------------
// OUT_MODE: 0 = bf16 row-major; 2 = fp32 row-major; 3 = fused QKV routing.
// Mode 3 writes K and V in MFMA-FRAGMENT order via LDS-staged coalesced epilogue.
//   Kf[((b*4+kvh)*64 + kvt)*8 + ck][lane = hi*32+ql][j]
//   Vf[(((b*4+kvh)*64 + kvt)*2 + ks)*4 + db][lane][j]
template<int OUT_MODE>
__global__ __launch_bounds__(256) void gemm_bt(const u16* __restrict__ A, const u16* __restrict__ B,
                                               void* __restrict__ Cout, int M, int N, int Kd,
                                               u16* __restrict__ Kout, u16* __restrict__ Vtout) {
  __shared__ u16 smem[(OUT_MODE == 3) ? 16384 : 8192];
  u16* sA = smem;
  u16* sB = smem + 4096;
  const int tid = threadIdx.x;
  const int l = tid & 63, w = tid >> 6;
  const int wr = w >> 1, wc = w & 1;
  const int g = l >> 4, c = l & 15;
  const int tm = blockIdx.y * 128, tn = blockIdx.x * 128;

  f32x4 acc[4][4] = {};

  const int r0 = tid >> 2, cc = (tid & 3) << 3;

  for (int k0 = 0; k0 < Kd; k0 += 32) {
    __syncthreads();
    {
      const u16* srcA0 = A + (size_t)(tm + r0) * Kd + k0 + cc;
      const u16* srcB0 = B + (size_t)(tn + r0) * Kd + k0 + cc;
      gload_lds16(srcA0, (char*)sA + w * 1024);
      gload_lds16(srcB0, (char*)sB + w * 1024);
      gload_lds16(srcA0 + (size_t)64 * Kd, (char*)sA + 4096 + w * 1024);
      gload_lds16(srcB0 + (size_t)64 * Kd, (char*)sB + 4096 + w * 1024);
    }
    __syncthreads();

    bf16x8 af[4], bfr[4];
#pragma unroll
    for (int m = 0; m < 4; ++m)
      af[m] = *(const bf16x8*)(sA + (wr * 64 + m * 16 + c) * 32 + g * 8);
#pragma unroll
    for (int n = 0; n < 4; ++n)
      bfr[n] = *(const bf16x8*)(sB + (wc * 64 + n * 16 + c) * 32 + g * 8);
#pragma unroll
    for (int m = 0; m < 4; ++m)
#pragma unroll
      for (int n = 0; n < 4; ++n)
        acc[m][n] = __builtin_amdgcn_mfma_f32_16x16x32_bf16(af[m], bfr[n], acc[m][n], 0, 0, 0);
  }

  if constexpr (OUT_MODE == 3) {
    if (tn >= 2048) {
      // ---- K/V fragment-order epilogue via LDS staging ----
      const bool isK = tn < 2560;
      __syncthreads();  // all MFMA LDS reads done before smem reuse
#pragma unroll
      for (int m = 0; m < 4; ++m)
#pragma unroll
        for (int n = 0; n < 4; ++n)
#pragma unroll
          for (int i = 0; i < 4; ++i) {
            int lr = wr * 64 + m * 16 + g * 4 + i;   // local row (kv position s)
            int lc = wc * 64 + n * 16 + c;           // local col (k or d)
            int off;
            if (isK)
              off = ((lr >> 5) << 12) + ((lc >> 4) << 9) + (((lc >> 3) & 1) << 8) +
                    ((lr & 31) << 3) + (lc & 7);
            else
              off = ((lr >> 5) << 12) + (((lr >> 4) & 1) << 11) + ((lc >> 5) << 9) +
                    (((lr >> 3) & 1) << 8) + ((lc & 31) << 3) + (lr & 7);
            smem[off] = f2b(acc[m][n][i]);
          }
      __syncthreads();
      const int e0 = tn - (isK ? 2048 : 2560);
      const int bb = tm >> 11;
      u16* dstbase = (isK ? Kout : Vtout) +
                     ((((size_t)(bb * 4 + (e0 >> 7)) * 64 + ((tm & 2047) >> 5))) << 12);
#pragma unroll
      for (int ps = 0; ps < 8; ++ps) {
        int idx = ps * 2048 + tid * 8;
        *(bf16x8*)(dstbase + idx) = *(const bf16x8*)(smem + idx);
      }
      return;
    }
  }

#pragma unroll
  for (int m = 0; m < 4; ++m)
#pragma unroll
    for (int n = 0; n < 4; ++n)
#pragma unroll
      for (int i = 0; i < 4; ++i) {
        int row = tm + wr * 64 + m * 16 + g * 4 + i;
        int col = tn + wc * 64 + n * 16 + c;
        float v = acc[m][n][i];
        if constexpr (OUT_MODE == 2) {
          ((float*)Cout)[(size_t)row * N + col] = v;
        } else {
          ((u16*)Cout)[(size_t)row * 2048 + col] = f2b(v);  // Q / bf16 row-major (ld 2048)
        }
      }
}

// ---------------- causal GQA flash attention: 32x32 swapped-operand, fully balanced ----
// grid (32, 32), block 256 (4 waves). TWO sequential phases per block: subtile x, then 63-x.
// Within each phase, wave w takes kv-tiles kv = (w + 4i)*32 (4-way split, 2-stage merge).
// Per-wave total work = (x+1)/4 + (64-x)/4 = 16.25 +- 1.5 units — EVERY wave in the grid
// equal; every block equal (65 units). 4096 waves, 4 blocks/CU co-resident.
// (r12 was block-balanced only -> 80us; r13 wave-balanced only -> 97us; this does both.)
// K/V are MFMA-fragment-ordered: every load = 64 lanes x contiguous 16 B.
// NOTE: min-waves arg MUST be 2 — (256,4) caps VGPR at 64 and spills (round 8: 5x regression).
__global__ __launch_bounds__(256, 2) void attn_fwd(const u16* __restrict__ Q, const u16* __restrict__ Kf,
                                                   const u16* __restrict__ Vf, u16* __restrict__ AO) {
  const int l = threadIdx.x & 63, w = threadIdx.x >> 6;
  const int ql = l & 31, hi = l >> 5;
  const int bh = blockIdx.y;
  const int b = bh >> 4, h = bh & 15;
  const int kvh = h >> 2;

  __shared__ float4 mO[2][16][64];   // [slot][elem][lane]
  __shared__ float mML[2][2][64];

  const float sm = 0.08838834764831845f * 1.4426950408889634f;  // 1/sqrt(128) * log2(e)

  // fragment-ordered bases: 64 kv-tiles x 4096 u16 per (b,kvh)
  const u16* Kfb = Kf + (size_t)(b * 4 + kvh) * 64 * 4096 + l * 8;
  const u16* Vfb = Vf + (size_t)(b * 4 + kvh) * 64 * 4096 + l * 8;

  const int x = (int)blockIdx.x;

#define LOADK(KF, KV0)                                                        \
  do {                                                                        \
    const u16* kb_ = Kfb + (size_t)((KV0) >> 5) * 4096;                       \
    _Pragma("unroll") for (int ck = 0; ck < 8; ++ck)                          \
        KF[ck] = *(const bf16x8*)(kb_ + ck * 512);                            \
  } while (0)

#define COMPUTE(KF, KV0)                                                      \
  do {                                                                        \
    bf16x8 vtf[2][4];                                                         \
    {                                                                         \
      const u16* vb_ = Vfb + (size_t)((KV0) >> 5) * 4096;                     \
      _Pragma("unroll") for (int ks = 0; ks < 2; ++ks)                        \
      _Pragma("unroll") for (int db = 0; db < 4; ++db)                        \
          vtf[ks][db] = *(const bf16x8*)(vb_ + (ks * 4 + db) * 512);          \
    }                                                                         \
    f32x16 sacc = {};                                                         \
    __builtin_amdgcn_s_setprio(1);                                            \
    _Pragma("unroll") for (int ck = 0; ck < 8; ++ck)                          \
        sacc = __builtin_amdgcn_mfma_f32_32x32x16_bf16(KF[ck], qf[ck], sacc, 0, 0, 0); \
    __builtin_amdgcn_s_setprio(0);                                            \
    if ((KV0) == q0) { /* diagonal: mask kv > q */                            \
      _Pragma("unroll") for (int r = 0; r < 16; ++r) {                        \
        int crow = (r & 3) + 8 * (r >> 2) + 4 * hi;                           \
        if (crow > ql) sacc[r] = -1e30f;                                      \
      }                                                                       \
    }                                                                         \
    float t0 = fmaxf(sacc[0], sacc[1]), t1 = fmaxf(sacc[2], sacc[3]);         \
    float t2 = fmaxf(sacc[4], sacc[5]), t3 = fmaxf(sacc[6], sacc[7]);         \
    float t4 = fmaxf(sacc[8], sacc[9]), t5 = fmaxf(sacc[10], sacc[11]);       \
    float t6 = fmaxf(sacc[12], sacc[13]), t7 = fmaxf(sacc[14], sacc[15]);     \
    float mx = fmaxf(fmaxf(fmaxf(t0, t1), fmaxf(t2, t3)),                     \
                     fmaxf(fmaxf(t4, t5), fmaxf(t6, t7)));                    \
    mx = xhalf_max(mx);                                                       \
    float p[16];                                                              \
    _Pragma("unroll") for (int r = 0; r < 16; ++r)                            \
        p[r] = exp2f((sacc[r] - mrow) * sm);                                  \
    if (!__all((mx - mrow) * sm <= 8.0f)) { /* T13 defer-max */               \
      float mnew = fmaxf(mrow, mx);                                           \
      float rs = exp2f((mrow - mnew) * sm);                                   \
      mrow = mnew;                                                            \
      lrow *= rs;                                                             \
      _Pragma("unroll") for (int db = 0; db < 4; ++db)                        \
      _Pragma("unroll") for (int r = 0; r < 16; ++r) acc[db][r] *= rs;        \
      _Pragma("unroll") for (int r = 0; r < 16; ++r)                          \
          p[r] = exp2f((sacc[r] - mrow) * sm);                                \
    }                                                                         \
    float s0 = p[0] + p[1], s1 = p[2] + p[3], s2 = p[4] + p[5], s3 = p[6] + p[7]; \
    float s4 = p[8] + p[9], s5 = p[10] + p[11], s6 = p[12] + p[13], s7 = p[14] + p[15]; \
    float psum = ((s0 + s1) + (s2 + s3)) + ((s4 + s5) + (s6 + s7));           \
    lrow += xhalf_sum(psum);                                                  \
    u32 a0 = pktrunc(p[0], p[1]), a1 = pktrunc(p[2], p[3]);                   \
    u32 a2 = pktrunc(p[4], p[5]), a3 = pktrunc(p[6], p[7]);                   \
    u32 b0 = pktrunc(p[8], p[9]), b1 = pktrunc(p[10], p[11]);                 \
    u32 b2 = pktrunc(p[12], p[13]), b3 = pktrunc(p[14], p[15]);               \
    union { bf16x8 v; u32 u[4]; } pa0, pa1;                                   \
    xexchange(hi, a0, a1, a2, a3, pa0.u);                                     \
    xexchange(hi, b0, b1, b2, b3, pa1.u);                                     \
    __builtin_amdgcn_s_setprio(1);                                            \
    _Pragma("unroll") for (int db = 0; db < 4; ++db) {                        \
      acc[db] = __builtin_amdgcn_mfma_f32_32x32x16_bf16(vtf[0][db], pa0.v, acc[db], 0, 0, 0); \
      acc[db] = __builtin_amdgcn_mfma_f32_32x32x16_bf16(vtf[1][db], pa1.v, acc[db], 0, 0, 0); \
    }                                                                         \
    __builtin_amdgcn_s_setprio(0);                                            \
  } while (0)

#define PUBLISH(SLOT)                                                         \
  do {                                                                        \
    _Pragma("unroll") for (int db = 0; db < 4; ++db)                          \
    _Pragma("unroll") for (int rq = 0; rq < 4; ++rq) {                        \
      float4 v;                                                               \
      v.x = acc[db][rq * 4 + 0];                                              \
      v.y = acc[db][rq * 4 + 1];                                              \
      v.z = acc[db][rq * 4 + 2];                                              \
      v.w = acc[db][rq * 4 + 3];                                              \
      mO[SLOT][db * 4 + rq][l] = v;                                           \
    }                                                                         \
    mML[SLOT][0][l] = mrow;                                                   \
    mML[SLOT][1][l] = lrow;                                                   \
  } while (0)

#define MERGE(SLOT)                                                           \
  do {                                                                        \
    float m1 = mML[SLOT][0][l], l1 = mML[SLOT][1][l];                         \
    float mnew = fmaxf(mrow, m1);                                             \
    float f0 = exp2f((mrow - mnew) * sm);                                     \
    float f1 = exp2f((m1 - mnew) * sm);                                       \
    mrow = mnew;                                                              \
    lrow = lrow * f0 + l1 * f1;                                               \
    _Pragma("unroll") for (int db = 0; db < 4; ++db)                          \
    _Pragma("unroll") for (int rq = 0; rq < 4; ++rq) {                        \
      float4 o1 = mO[SLOT][db * 4 + rq][l];                                   \
      acc[db][rq * 4 + 0] = acc[db][rq * 4 + 0] * f0 + o1.x * f1;             \
      acc[db][rq * 4 + 1] = acc[db][rq * 4 + 1] * f0 + o1.y * f1;             \
      acc[db][rq * 4 + 2] = acc[db][rq * 4 + 2] * f0 + o1.z * f1;             \
      acc[db][rq * 4 + 3] = acc[db][rq * 4 + 3] * f0 + o1.w * f1;             \
    }                                                                         \
  } while (0)

  for (int phase = 0; phase < 2; ++phase) {
    const int t = phase ? (63 - x) : x;
    const int q0 = t * 32;

    // Q fragments (B-operand of QK: col=q=lane&31, k = ck*16 + hi*8 + j)
    bf16x8 qf[8];
    {
      const u16* qb = Q + ((size_t)(b * 2048 + q0 + ql)) * 2048 + h * 128 + hi * 8;
#pragma unroll
      for (int ck = 0; ck < 8; ++ck) qf[ck] = *(const bf16x8*)(qb + ck * 16);
    }

    f32x16 acc[4] = {};  // O^T[d = db*32 + crow(r)][q = q0 + (lane&31)]
    float mrow = -1e30f, lrow = 0.f;

    bf16x8 kfa[8], kfb[8];

    // kv loop: wave w takes tiles kv0 = w*32, (w+4)*32, ... while kv0 <= q0 (K dbuf)
    int kv0 = w * 32;
    if (kv0 <= q0) {
      LOADK(kfa, kv0);
      while (true) {
        bool more = kv0 + 128 <= q0;
        if (more) LOADK(kfb, kv0 + 128);
        COMPUTE(kfa, kv0);
        if (!more) break;
        kv0 += 128;
        more = kv0 + 128 <= q0;
        if (more) LOADK(kfa, kv0 + 128);
        COMPUTE(kfb, kv0);
        if (!more) break;
        kv0 += 128;
      }
    }

    // ---- 2-stage pairwise merge: (0<-2, 1<-3), then (0<-1); wave 0 stores ----
    if (w >= 2) PUBLISH(w - 2);
    __syncthreads();
    if (w < 2) MERGE(w);
    __syncthreads();
    if (w == 1) PUBLISH(0);
    __syncthreads();
    if (w == 0) {
      MERGE(0);
      float inv = 1.0f / lrow;
      u16* ob = AO + (size_t)(b * 2048 + q0 + ql) * 2048 + h * 128 + hi * 4;
#pragma unroll
      for (int db = 0; db < 4; ++db)
#pragma unroll
        for (int rq = 0; rq < 4; ++rq) {
          ushort4 o;
          o.x = f2b(acc[db][rq * 4 + 0] * inv);
          o.y = f2b(acc[db][rq * 4 + 1] * inv);
          o.z = f2b(acc[db][rq * 4 + 2] * inv);
          o.w = f2b(acc[db][rq * 4 + 3] * inv);
          *(ushort4*)(ob + db * 32 + rq * 8) = o;
        }
    }
    __syncthreads();  // slot reuse guard before next phase's PUBLISH
  }
#undef LOADK
#undef COMPUTE
#undef PUBLISH
#undef MERGE
}

// ---------------- host ----------------
extern "C" void kernel_launch(void* const* d_in, const int* in_sizes, int n_in,
                              void* d_out, int out_size, void* d_ws, size_t ws_size,
                              hipStream_t stream) {
  const float* X = (const float*)d_in[0];
  const float* Wq = (const float*)d_in[1];
  const float* Wk = (const float*)d_in[2];
  const float* Wv = (const float*)d_in[3];
  const float* Wo = (const float*)d_in[4];

  u16* ws = (u16*)d_ws;
  const size_t nX = 8388608;   // 2*2048*2048
  const size_t nWq = 4194304;  // 2048*2048
  const size_t nWk = 1048576;  // 512*2048
  u16* Xb = ws;
  u16* Wqb = Xb + nX;          // [Wq|Wk|Wv] contiguous = fused 3072x2048 weight
  u16* Wkb = Wqb + nWq;
  u16* Wvb = Wkb + nWk;
  u16* Wob = Wvb + nWk;
  u16* Qb = Wob + nWq;
  u16* Kfb = Qb + nX;          // K in fragment order (2M u16)
  u16* Vfb = Kfb + 2097152;    // V in fragment order (2M u16)
  u16* AOb = Vfb + 2097152;
  if (ws_size < (size_t)(39845888) * 2) return;

  cvt_bf16<<<2048, 256, 0, stream>>>(X, Xb, (int)nX);
  cvt_w4<<<2048, 256, 0, stream>>>(Wq, Wk, Wv, Wo, Wqb);

  // fused QKV projection: C[4096][3072] routed to Q / K-frag / V-frag
  gemm_bt<3><<<dim3(24, 32), 256, 0, stream>>>(Xb, Wqb, Qb, 4096, 3072, 2048, Kfb, Vfb);

  attn_fwd<<<dim3(32, 32), 256, 0, stream>>>(Qb, Kfb, Vfb, AOb);

  // output projection -> fp32 d_out
  gemm_bt<2><<<dim3(16, 32), 256, 0, stream>>>(AOb, Wob, d_out, 4096, 2048, 2048, nullptr, nullptr);
}

// Round 15
// 198.921 us; speedup vs baseline: 1.1695x; 1.0881x over previous
//
#include <hip/hip_runtime.h>

typedef unsigned short u16;
typedef unsigned int u32;
typedef __attribute__((ext_vector_type(4))) float f32x4;
typedef __attribute__((ext_vector_type(16))) float f32x16;
typedef __attribute__((ext_vector_type(8))) short bf16x8;

// Problem sizes (fixed): B=2, S=2048, D=2048, NH=16, NKV=4, HD=128

__device__ __forceinline__ u16 f2b(float f) {
  u32 u = __builtin_bit_cast(u32, f);
  u = (u + 0x7fffu + ((u >> 16) & 1u)) >> 16;  // RNE
  return (u16)u;
}

__device__ __forceinline__ void gload_lds16(const void* g, void* l) {
  __builtin_amdgcn_global_load_lds((const __attribute__((address_space(1))) u32*)g,
                                   (__attribute__((address_space(3))) u32*)l, 16, 0, 0);
}

// ---- cross-half (lane <-> lane^32) exchange via v_permlane32_swap_b32 (VALU pipe) ----
#if __has_builtin(__builtin_amdgcn_permlane32_swap)
#define HAS_PLS 1
__device__ __forceinline__ void pls(u32 x, u32 y, u32& rx, u32& ry) {
  auto r = __builtin_amdgcn_permlane32_swap(x, y, false, false);
  rx = (u32)r[0];
  ry = (u32)r[1];
}
#endif

__device__ __forceinline__ float xhalf_max(float v) {
#ifdef HAS_PLS
  u32 a, b;
  pls(__builtin_bit_cast(u32, v), __builtin_bit_cast(u32, v), a, b);
  return fmaxf(__builtin_bit_cast(float, a), __builtin_bit_cast(float, b));
#else
  return fmaxf(v, __shfl_xor(v, 32));
#endif
}

__device__ __forceinline__ float xhalf_sum(float v) {
#ifdef HAS_PLS
  u32 a, b;
  pls(__builtin_bit_cast(u32, v), __builtin_bit_cast(u32, v), a, b);
  return __builtin_bit_cast(float, a) + __builtin_bit_cast(float, b);
#else
  return v + __shfl_xor(v, 32);
#endif
}

// P-fragment redistribution across lane halves
__device__ __forceinline__ void xexchange(int hi, u32 a0, u32 a1, u32 a2, u32 a3, u32* o) {
#ifdef HAS_PLS
  pls(a0, a2, o[0], o[2]);
  pls(a1, a3, o[1], o[3]);
#else
  u32 xa0 = (u32)__shfl_xor((int)a0, 32), xa1 = (u32)__shfl_xor((int)a1, 32);
  u32 xa2 = (u32)__shfl_xor((int)a2, 32), xa3 = (u32)__shfl_xor((int)a3, 32);
  o[0] = hi ? xa2 : a0;
  o[1] = hi ? xa3 : a1;
  o[2] = hi ? a2 : xa0;
  o[3] = hi ? a3 : xa1;
#endif
}

// truncating bf16 pair pack (P in [0,1]; <=2^-8 rel err, cheap: 3 ops)
__device__ __forceinline__ u32 pktrunc(float lo, float hif) {
  return (__builtin_bit_cast(u32, lo) >> 16) | (__builtin_bit_cast(u32, hif) & 0xffff0000u);
}

// ---------------- fp32 -> bf16 conversion ----------------
__global__ void cvt_bf16(const float* __restrict__ src, u16* __restrict__ dst, int n) {
  int stride = gridDim.x * blockDim.x * 4;
  for (int idx = (blockIdx.x * blockDim.x + threadIdx.x) * 4; idx < n; idx += stride) {
    float4 v = *(const float4*)(src + idx);
    ushort4 o;
    o.x = f2b(v.x); o.y = f2b(v.y); o.z = f2b(v.z); o.w = f2b(v.w);
    *(ushort4*)(dst + idx) = o;
  }
}

// fused weight conversion: dst = [Wq | Wk | Wv | Wo] contiguous
__global__ void cvt_w4(const float* __restrict__ Wq, const float* __restrict__ Wk,
                       const float* __restrict__ Wv, const float* __restrict__ Wo,
                       u16* __restrict__ dst) {
  const int total = 10485760;
  int stride = gridDim.x * blockDim.x * 4;
  for (int idx = (blockIdx.x * blockDim.x + threadIdx.x) * 4; idx < total; idx += stride) {
    const float* src;
    int off;
    if (idx < 4194304) { src = Wq; off = idx; }
    else if (idx < 5242880) { src = Wk; off = idx - 4194304; }
    else if (idx < 6291456) { src = Wv; off = idx - 5242880; }
    else { src = Wo; off = idx - 6291456; }
    float4 v = *(const float4*)(src + off);
    ushort4 o;
    o.x = f2b(v.x); o.y = f2b(v.y); o.z = f2b(v.z); o.w = f2b(v.w);
    *(ushort4*)(dst + idx) = o;
  }
}

// ---------------- 256x256 8-phase GEMM: C[M,N] = A[M,K] * B[N,K]^T ----------------
// 512 threads (8 waves, 2M x 4N), BK=64, 128 KB LDS double-buffer, T2 XOR-swizzle
// (both-sides: inverse-swizzled gload source + swizzled ds_read), counted vmcnt
// (4 at q0 / 6 at q2, in-order-safe by construction), raw s_barrier, T5 setprio.
// OUT_MODE 2 = fp32 row-major; 3 = fused QKV routing (Q row-major, K/V fragment order
// via 128KB-LDS-staged coalesced epilogue reusing the dbuf space after the K-loop).
template<int OUT_MODE>
__global__ __launch_bounds__(512) void gemm256(const u16* __restrict__ A, const u16* __restrict__ B,
                                               void* __restrict__ Cout, int M, int N, int Kd,
                                               u16* __restrict__ Kout, u16* __restrict__ Vout) {
  __shared__ u16 smem[65536];  // 128 KB: [slot0: A 16384 | B 16384][slot1: ...]
  const int tid = threadIdx.x;
  const int l = tid & 63, w = tid >> 6;
  const int c = l & 15, g = l >> 4;
  const int wr = w >> 2, wc = w & 3;
  const int tm = blockIdx.y * 256, tn = blockIdx.x * 256;

  // staging geometry: one round = 8KB = 64 rows x 64 u16; thread covers 8 u16
  const int lr = tid >> 3;           // row within round
  const int lcol = (tid & 7) * 8;    // dest u16 col
  const int scol = lcol ^ (((lr >> 1) & 3) << 4);  // inverse-swizzled source col
  const int swc = ((c >> 1) & 3) << 4;             // read-side swizzle (row bits = c)

#define BARX() do { __builtin_amdgcn_s_barrier(); asm volatile("" ::: "memory"); } while (0)
#define STG(SRC, GROW0, LDS0) \
  gload_lds16((SRC) + (size_t)((GROW0) + lr) * Kd + k0n + scol, (LDS0) + lr * 64 + lcol)

  f32x4 acc[8][4] = {};

  // prologue: tile 0 -> slot 0; round order: B0,B64,B128,B192, A0,A128, A64,A192
  {
    const int k0n = 0;
    u16* sAn = smem;
    u16* sBn = smem + 16384;
    STG(B, tn + 0, sBn); STG(B, tn + 64, sBn + 64 * 64);
    STG(B, tn + 128, sBn + 128 * 64); STG(B, tn + 192, sBn + 192 * 64);
    STG(A, tm + 0, sAn); STG(A, tm + 128, sAn + 128 * 64);
    STG(A, tm + 64, sAn + 64 * 64); STG(A, tm + 192, sAn + 192 * 64);
  }

  const int nt = Kd >> 6;
  for (int t = 0; t < nt; ++t) {
    const int slot = t & 1;
    u16* sAc = smem + slot * 32768;
    u16* sBc = sAc + 16384;
    u16* sAn = smem + (slot ^ 1) * 32768;
    u16* sBn = sAn + 16384;
    const int k0n = (t + 1) << 6;
    const bool st = (t + 1) < nt;

    bf16x8 bfr[4][2], af[2][2];

#define APH(q)                                                                  \
  do {                                                                          \
    _Pragma("unroll") for (int m2 = 0; m2 < 2; ++m2)                            \
    _Pragma("unroll") for (int kk = 0; kk < 2; ++kk)                            \
        af[m2][kk] = *(const bf16x8*)(sAc + (wr * 128 + (q) * 32 + m2 * 16 + c) * 64 + \
                                      ((kk * 32 + g * 8) ^ swc));               \
    __builtin_amdgcn_s_setprio(1);                                              \
    _Pragma("unroll") for (int m2 = 0; m2 < 2; ++m2)                            \
    _Pragma("unroll") for (int n = 0; n < 4; ++n)                               \
    _Pragma("unroll") for (int kk = 0; kk < 2; ++kk)                            \
        acc[(q) * 2 + m2][n] = __builtin_amdgcn_mfma_f32_16x16x32_bf16(         \
            af[m2][kk], bfr[n][kk], acc[(q) * 2 + m2][n], 0, 0, 0);             \
    __builtin_amdgcn_s_setprio(0);                                              \
  } while (0)

    // ---- q0 ----
    BARX();  // prior group's reads of sAn/sBn are done (lgkm'd before their MFMA)
    if (st) { STG(B, tn + 0, sBn); STG(B, tn + 64, sBn + 64 * 64); }
    if (st) asm volatile("s_waitcnt vmcnt(4)" ::: "memory");
    else    asm volatile("s_waitcnt vmcnt(2)" ::: "memory");
    BARX();  // publish tile-t: B(all), A(0-63), A(128-191)
#pragma unroll
    for (int n = 0; n < 4; ++n)
#pragma unroll
      for (int kk = 0; kk < 2; ++kk)
        bfr[n][kk] = *(const bf16x8*)(sBc + (wc * 64 + n * 16 + c) * 64 +
                                      ((kk * 32 + g * 8) ^ swc));
    APH(0);
    // ---- q1 ----
    if (st) { STG(B, tn + 128, sBn + 128 * 64); STG(B, tn + 192, sBn + 192 * 64); }
    APH(1);
    // ---- q2 ----
    if (st) { STG(A, tm + 0, sAn); STG(A, tm + 128, sAn + 128 * 64); }
    if (st) asm volatile("s_waitcnt vmcnt(6)" ::: "memory");
    else    asm volatile("s_waitcnt vmcnt(0)" ::: "memory");
    BARX();  // publish tile-t: A(64-127), A(192-255)
    APH(2);
    // ---- q3 ----
    if (st) { STG(A, tm + 64, sAn + 64 * 64); STG(A, tm + 192, sAn + 192 * 64); }
    APH(3);
#undef APH
  }

  if constexpr (OUT_MODE == 3) {
    if (tn >= 2048) {
      // ---- K/V fragment-order epilogue: scatter to 128KB LDS, then 16x8KB coalesced copy
      const bool isK = tn < 2560;
      BARX();  // all waves' K-loop ds_reads done before smem reuse
#pragma unroll
      for (int mi = 0; mi < 8; ++mi)
#pragma unroll
        for (int n = 0; n < 4; ++n)
#pragma unroll
          for (int i = 0; i < 4; ++i) {
            int s = wr * 128 + (mi >> 1) * 32 + (mi & 1) * 16 + g * 4 + i;  // kv row
            int e = wc * 64 + n * 16 + c;                                    // k or d col
            int chunk = (e >> 7) * 8 + (s >> 5);
            int off;
            if (isK) {
              int k = e & 127;
              off = chunk * 4096 + (k >> 4) * 512 + ((k >> 3) & 1) * 256 + (s & 31) * 8 + (k & 7);
            } else {
              int d = e & 127;
              off = chunk * 4096 + (((s >> 4) & 1) * 4 + (d >> 5)) * 512 + ((s >> 3) & 1) * 256 +
                    (d & 31) * 8 + (s & 7);
            }
            smem[off] = f2b(acc[mi][n][i]);
          }
      BARX();
      const int kvh_base = (tn - (isK ? 2048 : 2560)) >> 7;
      const int bb = tm >> 11;
      const int kvt0 = (tm & 2047) >> 5;
      u16* Out = isK ? Kout : Vout;
#pragma unroll
      for (int ch = 0; ch < 16; ++ch) {
        u16* dst = Out + (size_t)((bb * 4 + kvh_base + (ch >> 3)) * 64 + kvt0 + (ch & 7)) * 4096;
        *(bf16x8*)(dst + tid * 8) = *(const bf16x8*)(smem + ch * 4096 + tid * 8);
      }
      return;
    }
    // Q tiles: bf16 row-major, ld 2048
#pragma unroll
    for (int mi = 0; mi < 8; ++mi)
#pragma unroll
      for (int n = 0; n < 4; ++n)
#pragma unroll
        for (int i = 0; i < 4; ++i) {
          int row = tm + wr * 128 + (mi >> 1) * 32 + (mi & 1) * 16 + g * 4 + i;
          int col = tn + wc * 64 + n * 16 + c;
          ((u16*)Cout)[(size_t)row * 2048 + col] = f2b(acc[mi][n][i]);
        }
    return;
  }

  // OUT_MODE 2: fp32 row-major
#pragma unroll
  for (int mi = 0; mi < 8; ++mi)
#pragma unroll
    for (int n = 0; n < 4; ++n)
#pragma unroll
      for (int i = 0; i < 4; ++i) {
        int row = tm + wr * 128 + (mi >> 1) * 32 + (mi & 1) * 16 + g * 4 + i;
        int col = tn + wc * 64 + n * 16 + c;
        ((float*)Cout)[(size_t)row * N + col] = acc[mi][n][i];
      }
#undef STG
#undef BARX
}

// ---------------- causal GQA flash attention: 32x32 swapped-operand, fully balanced ----
// grid (32, 32), block 256 (4 waves). TWO sequential phases per block: subtile x, then 63-x.
// Within each phase, wave w takes kv-tiles kv = (w + 4i)*32 (4-way split, 2-stage merge).
// K/V are MFMA-fragment-ordered: every load = 64 lanes x contiguous 16 B.
// NOTE: min-waves arg MUST be 2 — (256,4) caps VGPR at 64 and spills (round 8: 5x regression).
__global__ __launch_bounds__(256, 2) void attn_fwd(const u16* __restrict__ Q, const u16* __restrict__ Kf,
                                                   const u16* __restrict__ Vf, u16* __restrict__ AO) {
  const int l = threadIdx.x & 63, w = threadIdx.x >> 6;
  const int ql = l & 31, hi = l >> 5;
  const int bh = blockIdx.y;
  const int b = bh >> 4, h = bh & 15;
  const int kvh = h >> 2;

  __shared__ float4 mO[2][16][64];   // [slot][elem][lane]
  __shared__ float mML[2][2][64];

  const float sm = 0.08838834764831845f * 1.4426950408889634f;  // 1/sqrt(128) * log2(e)

  const u16* Kfb = Kf + (size_t)(b * 4 + kvh) * 64 * 4096 + l * 8;
  const u16* Vfb = Vf + (size_t)(b * 4 + kvh) * 64 * 4096 + l * 8;

  const int x = (int)blockIdx.x;

#define LOADK(KF, KV0)                                                        \
  do {                                                                        \
    const u16* kb_ = Kfb + (size_t)((KV0) >> 5) * 4096;                       \
    _Pragma("unroll") for (int ck = 0; ck < 8; ++ck)                          \
        KF[ck] = *(const bf16x8*)(kb_ + ck * 512);                            \
  } while (0)

#define COMPUTE(KF, KV0)                                                      \
  do {                                                                        \
    bf16x8 vtf[2][4];                                                         \
    {                                                                         \
      const u16* vb_ = Vfb + (size_t)((KV0) >> 5) * 4096;                     \
      _Pragma("unroll") for (int ks = 0; ks < 2; ++ks)                        \
      _Pragma("unroll") for (int db = 0; db < 4; ++db)                        \
          vtf[ks][db] = *(const bf16x8*)(vb_ + (ks * 4 + db) * 512);          \
    }                                                                         \
    f32x16 sacc = {};                                                         \
    __builtin_amdgcn_s_setprio(1);                                            \
    _Pragma("unroll") for (int ck = 0; ck < 8; ++ck)                          \
        sacc = __builtin_amdgcn_mfma_f32_32x32x16_bf16(KF[ck], qf[ck], sacc, 0, 0, 0); \
    __builtin_amdgcn_s_setprio(0);                                            \
    if ((KV0) == q0) { /* diagonal: mask kv > q */                            \
      _Pragma("unroll") for (int r = 0; r < 16; ++r) {                        \
        int crow = (r & 3) + 8 * (r >> 2) + 4 * hi;                           \
        if (crow > ql) sacc[r] = -1e30f;                                      \
      }                                                                       \
    }                                                                         \
    float t0 = fmaxf(sacc[0], sacc[1]), t1 = fmaxf(sacc[2], sacc[3]);         \
    float t2 = fmaxf(sacc[4], sacc[5]), t3 = fmaxf(sacc[6], sacc[7]);         \
    float t4 = fmaxf(sacc[8], sacc[9]), t5 = fmaxf(sacc[10], sacc[11]);       \
    float t6 = fmaxf(sacc[12], sacc[13]), t7 = fmaxf(sacc[14], sacc[15]);     \
    float mx = fmaxf(fmaxf(fmaxf(t0, t1), fmaxf(t2, t3)),                     \
                     fmaxf(fmaxf(t4, t5), fmaxf(t6, t7)));                    \
    mx = xhalf_max(mx);                                                       \
    float p[16];                                                              \
    _Pragma("unroll") for (int r = 0; r < 16; ++r)                            \
        p[r] = exp2f((sacc[r] - mrow) * sm);                                  \
    if (!__all((mx - mrow) * sm <= 8.0f)) { /* T13 defer-max */               \
      float mnew = fmaxf(mrow, mx);                                           \
      float rs = exp2f((mrow - mnew) * sm);                                   \
      mrow = mnew;                                                            \
      lrow *= rs;                                                             \
      _Pragma("unroll") for (int db = 0; db < 4; ++db)                        \
      _Pragma("unroll") for (int r = 0; r < 16; ++r) acc[db][r] *= rs;        \
      _Pragma("unroll") for (int r = 0; r < 16; ++r)                          \
          p[r] = exp2f((sacc[r] - mrow) * sm);                                \
    }                                                                         \
    float s0 = p[0] + p[1], s1 = p[2] + p[3], s2 = p[4] + p[5], s3 = p[6] + p[7]; \
    float s4 = p[8] + p[9], s5 = p[10] + p[11], s6 = p[12] + p[13], s7 = p[14] + p[15]; \
    float psum = ((s0 + s1) + (s2 + s3)) + ((s4 + s5) + (s6 + s7));           \
    lrow += xhalf_sum(psum);                                                  \
    u32 a0 = pktrunc(p[0], p[1]), a1 = pktrunc(p[2], p[3]);                   \
    u32 a2 = pktrunc(p[4], p[5]), a3 = pktrunc(p[6], p[7]);                   \
    u32 b0 = pktrunc(p[8], p[9]), b1 = pktrunc(p[10], p[11]);                 \
    u32 b2 = pktrunc(p[12], p[13]), b3 = pktrunc(p[14], p[15]);               \
    union { bf16x8 v; u32 u[4]; } pa0, pa1;                                   \
    xexchange(hi, a0, a1, a2, a3, pa0.u);                                     \
    xexchange(hi, b0, b1, b2, b3, pa1.u);                                     \
    __builtin_amdgcn_s_setprio(1);                                            \
    _Pragma("unroll") for (int db = 0; db < 4; ++db) {                        \
      acc[db] = __builtin_amdgcn_mfma_f32_32x32x16_bf16(vtf[0][db], pa0.v, acc[db], 0, 0, 0); \
      acc[db] = __builtin_amdgcn_mfma_f32_32x32x16_bf16(vtf[1][db], pa1.v, acc[db], 0, 0, 0); \
    }                                                                         \
    __builtin_amdgcn_s_setprio(0);                                            \
  } while (0)

#define PUBLISH(SLOT)                                                         \
  do {                                                                        \
    _Pragma("unroll") for (int db = 0; db < 4; ++db)                          \
    _Pragma("unroll") for (int rq = 0; rq < 4; ++rq) {                        \
      float4 v;                                                               \
      v.x = acc[db][rq * 4 + 0];                                              \
      v.y = acc[db][rq * 4 + 1];                                              \
      v.z = acc[db][rq * 4 + 2];                                              \
      v.w = acc[db][rq * 4 + 3];                                              \
      mO[SLOT][db * 4 + rq][l] = v;                                           \
    }                                                                         \
    mML[SLOT][0][l] = mrow;                                                   \
    mML[SLOT][1][l] = lrow;                                                   \
  } while (0)

#define MERGE(SLOT)                                                           \
  do {                                                                        \
    float m1 = mML[SLOT][0][l], l1 = mML[SLOT][1][l];                         \
    float mnew = fmaxf(mrow, m1);                                             \
    float f0 = exp2f((mrow - mnew) * sm);                                     \
    float f1 = exp2f((m1 - mnew) * sm);                                       \
    mrow = mnew;                                                              \
    lrow = lrow * f0 + l1 * f1;                                               \
    _Pragma("unroll") for (int db = 0; db < 4; ++db)                          \
    _Pragma("unroll") for (int rq = 0; rq < 4; ++rq) {                        \
      float4 o1 = mO[SLOT][db * 4 + rq][l];                                   \
      acc[db][rq * 4 + 0] = acc[db][rq * 4 + 0] * f0 + o1.x * f1;             \
      acc[db][rq * 4 + 1] = acc[db][rq * 4 + 1] * f0 + o1.y * f1;             \
      acc[db][rq * 4 + 2] = acc[db][rq * 4 + 2] * f0 + o1.z * f1;             \
      acc[db][rq * 4 + 3] = acc[db][rq * 4 + 3] * f0 + o1.w * f1;             \
    }                                                                         \
  } while (0)

  for (int phase = 0; phase < 2; ++phase) {
    const int t = phase ? (63 - x) : x;
    const int q0 = t * 32;

    bf16x8 qf[8];
    {
      const u16* qb = Q + ((size_t)(b * 2048 + q0 + ql)) * 2048 + h * 128 + hi * 8;
#pragma unroll
      for (int ck = 0; ck < 8; ++ck) qf[ck] = *(const bf16x8*)(qb + ck * 16);
    }

    f32x16 acc[4] = {};
    float mrow = -1e30f, lrow = 0.f;

    bf16x8 kfa[8], kfb[8];

    int kv0 = w * 32;
    if (kv0 <= q0) {
      LOADK(kfa, kv0);
      while (true) {
        bool more = kv0 + 128 <= q0;
        if (more) LOADK(kfb, kv0 + 128);
        COMPUTE(kfa, kv0);
        if (!more) break;
        kv0 += 128;
        more = kv0 + 128 <= q0;
        if (more) LOADK(kfa, kv0 + 128);
        COMPUTE(kfb, kv0);
        if (!more) break;
        kv0 += 128;
      }
    }

    if (w >= 2) PUBLISH(w - 2);
    __syncthreads();
    if (w < 2) MERGE(w);
    __syncthreads();
    if (w == 1) PUBLISH(0);
    __syncthreads();
    if (w == 0) {
      MERGE(0);
      float inv = 1.0f / lrow;
      u16* ob = AO + (size_t)(b * 2048 + q0 + ql) * 2048 + h * 128 + hi * 4;
#pragma unroll
      for (int db = 0; db < 4; ++db)
#pragma unroll
        for (int rq = 0; rq < 4; ++rq) {
          ushort4 o;
          o.x = f2b(acc[db][rq * 4 + 0] * inv);
          o.y = f2b(acc[db][rq * 4 + 1] * inv);
          o.z = f2b(acc[db][rq * 4 + 2] * inv);
          o.w = f2b(acc[db][rq * 4 + 3] * inv);
          *(ushort4*)(ob + db * 32 + rq * 8) = o;
        }
    }
    __syncthreads();  // slot reuse guard before next phase's PUBLISH
  }
#undef LOADK
#undef COMPUTE
#undef PUBLISH
#undef MERGE
}

// ---------------- host ----------------
extern "C" void kernel_launch(void* const* d_in, const int* in_sizes, int n_in,
                              void* d_out, int out_size, void* d_ws, size_t ws_size,
                              hipStream_t stream) {
  const float* X = (const float*)d_in[0];
  const float* Wq = (const float*)d_in[1];
  const float* Wk = (const float*)d_in[2];
  const float* Wv = (const float*)d_in[3];
  const float* Wo = (const float*)d_in[4];

  u16* ws = (u16*)d_ws;
  const size_t nX = 8388608;   // 2*2048*2048
  const size_t nWq = 4194304;  // 2048*2048
  const size_t nWk = 1048576;  // 512*2048
  u16* Xb = ws;
  u16* Wqb = Xb + nX;          // [Wq|Wk|Wv] contiguous = fused 3072x2048 weight
  u16* Wkb = Wqb + nWq;
  u16* Wvb = Wkb + nWk;
  u16* Wob = Wvb + nWk;
  u16* Qb = Wob + nWq;
  u16* Kfb = Qb + nX;          // K in fragment order (2M u16)
  u16* Vfb = Kfb + 2097152;    // V in fragment order (2M u16)
  u16* AOb = Vfb + 2097152;
  if (ws_size < (size_t)(39845888) * 2) return;

  cvt_bf16<<<2048, 256, 0, stream>>>(X, Xb, (int)nX);
  cvt_w4<<<2048, 256, 0, stream>>>(Wq, Wk, Wv, Wo, Wqb);

  // fused QKV projection (256^2 8-phase): C[4096][3072] routed to Q / K-frag / V-frag
  gemm256<3><<<dim3(12, 16), 512, 0, stream>>>(Xb, Wqb, Qb, 4096, 3072, 2048, Kfb, Vfb);

  attn_fwd<<<dim3(32, 32), 256, 0, stream>>>(Qb, Kfb, Vfb, AOb);

  // output projection (256^2 8-phase) -> fp32 d_out
  gemm256<2><<<dim3(8, 16), 512, 0, stream>>>(AOb, Wob, d_out, 4096, 2048, 2048, nullptr, nullptr);
}

// Round 16
// 198.097 us; speedup vs baseline: 1.1743x; 1.0042x over previous
//
#include <hip/hip_runtime.h>

typedef unsigned short u16;
typedef unsigned int u32;
typedef __attribute__((ext_vector_type(4))) float f32x4;
typedef __attribute__((ext_vector_type(16))) float f32x16;
typedef __attribute__((ext_vector_type(8))) short bf16x8;

// Problem sizes (fixed): B=2, S=2048, D=2048, NH=16, NKV=4, HD=128

__device__ __forceinline__ u16 f2b(float f) {
  u32 u = __builtin_bit_cast(u32, f);
  u = (u + 0x7fffu + ((u >> 16) & 1u)) >> 16;  // RNE
  return (u16)u;
}

__device__ __forceinline__ void gload_lds16(const void* g, void* l) {
  __builtin_amdgcn_global_load_lds((const __attribute__((address_space(1))) u32*)g,
                                   (__attribute__((address_space(3))) u32*)l, 16, 0, 0);
}

// ---- cross-half (lane <-> lane^32) exchange via v_permlane32_swap_b32 (VALU pipe) ----
#if __has_builtin(__builtin_amdgcn_permlane32_swap)
#define HAS_PLS 1
__device__ __forceinline__ void pls(u32 x, u32 y, u32& rx, u32& ry) {
  auto r = __builtin_amdgcn_permlane32_swap(x, y, false, false);
  rx = (u32)r[0];
  ry = (u32)r[1];
}
#endif

__device__ __forceinline__ float xhalf_max(float v) {
#ifdef HAS_PLS
  u32 a, b;
  pls(__builtin_bit_cast(u32, v), __builtin_bit_cast(u32, v), a, b);
  return fmaxf(__builtin_bit_cast(float, a), __builtin_bit_cast(float, b));
#else
  return fmaxf(v, __shfl_xor(v, 32));
#endif
}

__device__ __forceinline__ float xhalf_sum(float v) {
#ifdef HAS_PLS
  u32 a, b;
  pls(__builtin_bit_cast(u32, v), __builtin_bit_cast(u32, v), a, b);
  return __builtin_bit_cast(float, a) + __builtin_bit_cast(float, b);
#else
  return v + __shfl_xor(v, 32);
#endif
}

// P-fragment redistribution across lane halves
__device__ __forceinline__ void xexchange(int hi, u32 a0, u32 a1, u32 a2, u32 a3, u32* o) {
#ifdef HAS_PLS
  pls(a0, a2, o[0], o[2]);
  pls(a1, a3, o[1], o[3]);
#else
  u32 xa0 = (u32)__shfl_xor((int)a0, 32), xa1 = (u32)__shfl_xor((int)a1, 32);
  u32 xa2 = (u32)__shfl_xor((int)a2, 32), xa3 = (u32)__shfl_xor((int)a3, 32);
  o[0] = hi ? xa2 : a0;
  o[1] = hi ? xa3 : a1;
  o[2] = hi ? a2 : xa0;
  o[3] = hi ? a3 : xa1;
#endif
}

// truncating bf16 pair pack (P in [0,1]; <=2^-8 rel err, cheap: 3 ops)
__device__ __forceinline__ u32 pktrunc(float lo, float hif) {
  return (__builtin_bit_cast(u32, lo) >> 16) | (__builtin_bit_cast(u32, hif) & 0xffff0000u);
}

// ---------------- fp32 -> bf16 conversion ----------------
__global__ void cvt_bf16(const float* __restrict__ src, u16* __restrict__ dst, int n) {
  int stride = gridDim.x * blockDim.x * 4;
  for (int idx = (blockIdx.x * blockDim.x + threadIdx.x) * 4; idx < n; idx += stride) {
    float4 v = *(const float4*)(src + idx);
    ushort4 o;
    o.x = f2b(v.x); o.y = f2b(v.y); o.z = f2b(v.z); o.w = f2b(v.w);
    *(ushort4*)(dst + idx) = o;
  }
}

// fused weight conversion: dst = [Wq | Wk | Wv | Wo] contiguous
__global__ void cvt_w4(const float* __restrict__ Wq, const float* __restrict__ Wk,
                       const float* __restrict__ Wv, const float* __restrict__ Wo,
                       u16* __restrict__ dst) {
  const int total = 10485760;
  int stride = gridDim.x * blockDim.x * 4;
  for (int idx = (blockIdx.x * blockDim.x + threadIdx.x) * 4; idx < total; idx += stride) {
    const float* src;
    int off;
    if (idx < 4194304) { src = Wq; off = idx; }
    else if (idx < 5242880) { src = Wk; off = idx - 4194304; }
    else if (idx < 6291456) { src = Wv; off = idx - 5242880; }
    else { src = Wo; off = idx - 6291456; }
    float4 v = *(const float4*)(src + off);
    ushort4 o;
    o.x = f2b(v.x); o.y = f2b(v.y); o.z = f2b(v.z); o.w = f2b(v.w);
    *(ushort4*)(dst + idx) = o;
  }
}

// ---------------- 256x256 8-phase GEMM: C[M,N] = A[M,K] * B[N,K]^T ----------------
// 512 threads (8 waves, 2M x 4N), BK=64, 128 KB LDS double-buffer, T2 XOR-swizzle
// (both-sides), counted vmcnt (4 at q0 / 6 at q2), raw s_barrier, T5 setprio.
// OUT_MODE 2 = fp32 row-major; 3 = fused QKV routing (Q row-major, K/V fragment order
// via 128KB-LDS-staged coalesced epilogue reusing the dbuf space after the K-loop).
template<int OUT_MODE>
__global__ __launch_bounds__(512) void gemm256(const u16* __restrict__ A, const u16* __restrict__ B,
                                               void* __restrict__ Cout, int M, int N, int Kd,
                                               u16* __restrict__ Kout, u16* __restrict__ Vout) {
  __shared__ u16 smem[65536];  // 128 KB: [slot0: A 16384 | B 16384][slot1: ...]
  const int tid = threadIdx.x;
  const int l = tid & 63, w = tid >> 6;
  const int c = l & 15, g = l >> 4;
  const int wr = w >> 2, wc = w & 3;
  const int tm = blockIdx.y * 256, tn = blockIdx.x * 256;

  // staging geometry: one round = 8KB = 64 rows x 64 u16; thread covers 8 u16
  const int lr = tid >> 3;           // row within round
  const int lcol = (tid & 7) * 8;    // dest u16 col
  const int scol = lcol ^ (((lr >> 1) & 3) << 4);  // inverse-swizzled source col
  const int swc = ((c >> 1) & 3) << 4;             // read-side swizzle (row bits = c)

#define BARX() do { __builtin_amdgcn_s_barrier(); asm volatile("" ::: "memory"); } while (0)
#define STG(SRC, GROW0, LDS0) \
  gload_lds16((SRC) + (size_t)((GROW0) + lr) * Kd + k0n + scol, (LDS0) + lr * 64 + lcol)

  f32x4 acc[8][4] = {};

  // prologue: tile 0 -> slot 0; round order: B0,B64,B128,B192, A0,A128, A64,A192
  {
    const int k0n = 0;
    u16* sAn = smem;
    u16* sBn = smem + 16384;
    STG(B, tn + 0, sBn); STG(B, tn + 64, sBn + 64 * 64);
    STG(B, tn + 128, sBn + 128 * 64); STG(B, tn + 192, sBn + 192 * 64);
    STG(A, tm + 0, sAn); STG(A, tm + 128, sAn + 128 * 64);
    STG(A, tm + 64, sAn + 64 * 64); STG(A, tm + 192, sAn + 192 * 64);
  }

  const int nt = Kd >> 6;
  for (int t = 0; t < nt; ++t) {
    const int slot = t & 1;
    u16* sAc = smem + slot * 32768;
    u16* sBc = sAc + 16384;
    u16* sAn = smem + (slot ^ 1) * 32768;
    u16* sBn = sAn + 16384;
    const int k0n = (t + 1) << 6;
    const bool st = (t + 1) < nt;

    bf16x8 bfr[4][2], af[2][2];

#define APH(q)                                                                  \
  do {                                                                          \
    _Pragma("unroll") for (int m2 = 0; m2 < 2; ++m2)                            \
    _Pragma("unroll") for (int kk = 0; kk < 2; ++kk)                            \
        af[m2][kk] = *(const bf16x8*)(sAc + (wr * 128 + (q) * 32 + m2 * 16 + c) * 64 + \
                                      ((kk * 32 + g * 8) ^ swc));               \
    __builtin_amdgcn_s_setprio(1);                                              \
    _Pragma("unroll") for (int m2 = 0; m2 < 2; ++m2)                            \
    _Pragma("unroll") for (int n = 0; n < 4; ++n)                               \
    _Pragma("unroll") for (int kk = 0; kk < 2; ++kk)                            \
        acc[(q) * 2 + m2][n] = __builtin_amdgcn_mfma_f32_16x16x32_bf16(         \
            af[m2][kk], bfr[n][kk], acc[(q) * 2 + m2][n], 0, 0, 0);             \
    __builtin_amdgcn_s_setprio(0);                                              \
  } while (0)

    // ---- q0 ----
    BARX();  // prior group's reads of sAn/sBn are done (lgkm'd before their MFMA)
    if (st) { STG(B, tn + 0, sBn); STG(B, tn + 64, sBn + 64 * 64); }
    if (st) asm volatile("s_waitcnt vmcnt(4)" ::: "memory");
    else    asm volatile("s_waitcnt vmcnt(2)" ::: "memory");
    BARX();  // publish tile-t: B(all), A(0-63), A(128-191)
#pragma unroll
    for (int n = 0; n < 4; ++n)
#pragma unroll
      for (int kk = 0; kk < 2; ++kk)
        bfr[n][kk] = *(const bf16x8*)(sBc + (wc * 64 + n * 16 + c) * 64 +
                                      ((kk * 32 + g * 8) ^ swc));
    APH(0);
    // ---- q1 ----
    if (st) { STG(B, tn + 128, sBn + 128 * 64); STG(B, tn + 192, sBn + 192 * 64); }
    APH(1);
    // ---- q2 ----
    if (st) { STG(A, tm + 0, sAn); STG(A, tm + 128, sAn + 128 * 64); }
    if (st) asm volatile("s_waitcnt vmcnt(6)" ::: "memory");
    else    asm volatile("s_waitcnt vmcnt(0)" ::: "memory");
    BARX();  // publish tile-t: A(64-127), A(192-255)
    APH(2);
    // ---- q3 ----
    if (st) { STG(A, tm + 64, sAn + 64 * 64); STG(A, tm + 192, sAn + 192 * 64); }
    APH(3);
#undef APH
  }

  if constexpr (OUT_MODE == 3) {
    if (tn >= 2048) {
      // ---- K/V fragment-order epilogue: scatter to 128KB LDS, then 16x8KB coalesced copy
      const bool isK = tn < 2560;
      BARX();  // all waves' K-loop ds_reads done before smem reuse
#pragma unroll
      for (int mi = 0; mi < 8; ++mi)
#pragma unroll
        for (int n = 0; n < 4; ++n)
#pragma unroll
          for (int i = 0; i < 4; ++i) {
            int s = wr * 128 + (mi >> 1) * 32 + (mi & 1) * 16 + g * 4 + i;  // kv row
            int e = wc * 64 + n * 16 + c;                                    // k or d col
            int chunk = (e >> 7) * 8 + (s >> 5);
            int off;
            if (isK) {
              int k = e & 127;
              off = chunk * 4096 + (k >> 4) * 512 + ((k >> 3) & 1) * 256 + (s & 31) * 8 + (k & 7);
            } else {
              int d = e & 127;
              off = chunk * 4096 + (((s >> 4) & 1) * 4 + (d >> 5)) * 512 + ((s >> 3) & 1) * 256 +
                    (d & 31) * 8 + (s & 7);
            }
            smem[off] = f2b(acc[mi][n][i]);
          }
      BARX();
      const int kvh_base = (tn - (isK ? 2048 : 2560)) >> 7;
      const int bb = tm >> 11;
      const int kvt0 = (tm & 2047) >> 5;
      u16* Out = isK ? Kout : Vout;
#pragma unroll
      for (int ch = 0; ch < 16; ++ch) {
        u16* dst = Out + (size_t)((bb * 4 + kvh_base + (ch >> 3)) * 64 + kvt0 + (ch & 7)) * 4096;
        *(bf16x8*)(dst + tid * 8) = *(const bf16x8*)(smem + ch * 4096 + tid * 8);
      }
      return;
    }
    // Q tiles: bf16 row-major, ld 2048
#pragma unroll
    for (int mi = 0; mi < 8; ++mi)
#pragma unroll
      for (int n = 0; n < 4; ++n)
#pragma unroll
        for (int i = 0; i < 4; ++i) {
          int row = tm + wr * 128 + (mi >> 1) * 32 + (mi & 1) * 16 + g * 4 + i;
          int col = tn + wc * 64 + n * 16 + c;
          ((u16*)Cout)[(size_t)row * 2048 + col] = f2b(acc[mi][n][i]);
        }
    return;
  }

  // OUT_MODE 2: fp32 row-major
#pragma unroll
  for (int mi = 0; mi < 8; ++mi)
#pragma unroll
    for (int n = 0; n < 4; ++n)
#pragma unroll
      for (int i = 0; i < 4; ++i) {
        int row = tm + wr * 128 + (mi >> 1) * 32 + (mi & 1) * 16 + g * 4 + i;
        int col = tn + wc * 64 + n * 16 + c;
        ((float*)Cout)[(size_t)row * N + col] = acc[mi][n][i];
      }
#undef STG
#undef BARX
}

// ---------------- causal GQA flash attention: 32x32 swapped-operand, fully balanced ----
// grid (1024), block 256 (4 waves). XCD-affinity decode: xcd = id&7, bh = xcd + 8*(slot>>5),
// x = slot&31 — all 32 x-blocks of a given bh land on ONE XCD, so that bh's K/V working set
// (2 MB per (b,kvh)) stays L2-resident instead of being re-streamed from L3 by all 8 XCDs
// (logical K/V traffic is ~1.06 GB vs 45 MB HBM; r15 ran it at ~13 TB/s = L3-bound).
// TWO sequential phases per block: subtile x, then 63-x; wave w takes kv-tiles (w+4i)*32.
// K/V are MFMA-fragment-ordered: every load = 64 lanes x contiguous 16 B.
// NOTE: min-waves arg MUST be 2 — (256,4) caps VGPR at 64 and spills (round 8: 5x regression).
__global__ __launch_bounds__(256, 2) void attn_fwd(const u16* __restrict__ Q, const u16* __restrict__ Kf,
                                                   const u16* __restrict__ Vf, u16* __restrict__ AO) {
  const int l = threadIdx.x & 63, w = threadIdx.x >> 6;
  const int ql = l & 31, hi = l >> 5;
  const int id = (int)blockIdx.x;
  const int xcd = id & 7, slot = id >> 3;
  const int bh = xcd + 8 * (slot >> 5);
  const int x = slot & 31;
  const int b = bh >> 4, h = bh & 15;
  const int kvh = h >> 2;

  __shared__ float4 mO[2][16][64];   // [slot][elem][lane]
  __shared__ float mML[2][2][64];

  const float sm = 0.08838834764831845f * 1.4426950408889634f;  // 1/sqrt(128) * log2(e)

  const u16* Kfb = Kf + (size_t)(b * 4 + kvh) * 64 * 4096 + l * 8;
  const u16* Vfb = Vf + (size_t)(b * 4 + kvh) * 64 * 4096 + l * 8;

#define LOADK(KF, KV0)                                                        \
  do {                                                                        \
    const u16* kb_ = Kfb + (size_t)((KV0) >> 5) * 4096;                       \
    _Pragma("unroll") for (int ck = 0; ck < 8; ++ck)                          \
        KF[ck] = *(const bf16x8*)(kb_ + ck * 512);                            \
  } while (0)

#define COMPUTE(KF, KV0)                                                      \
  do {                                                                        \
    bf16x8 vtf[2][4];                                                         \
    {                                                                         \
      const u16* vb_ = Vfb + (size_t)((KV0) >> 5) * 4096;                     \
      _Pragma("unroll") for (int ks = 0; ks < 2; ++ks)                        \
      _Pragma("unroll") for (int db = 0; db < 4; ++db)                        \
          vtf[ks][db] = *(const bf16x8*)(vb_ + (ks * 4 + db) * 512);          \
    }                                                                         \
    f32x16 sacc = {};                                                         \
    __builtin_amdgcn_s_setprio(1);                                            \
    _Pragma("unroll") for (int ck = 0; ck < 8; ++ck)                          \
        sacc = __builtin_amdgcn_mfma_f32_32x32x16_bf16(KF[ck], qf[ck], sacc, 0, 0, 0); \
    __builtin_amdgcn_s_setprio(0);                                            \
    if ((KV0) == q0) { /* diagonal: mask kv > q */                            \
      _Pragma("unroll") for (int r = 0; r < 16; ++r) {                        \
        int crow = (r & 3) + 8 * (r >> 2) + 4 * hi;                           \
        if (crow > ql) sacc[r] = -1e30f;                                      \
      }                                                                       \
    }                                                                         \
    float t0 = fmaxf(sacc[0], sacc[1]), t1 = fmaxf(sacc[2], sacc[3]);         \
    float t2 = fmaxf(sacc[4], sacc[5]), t3 = fmaxf(sacc[6], sacc[7]);         \
    float t4 = fmaxf(sacc[8], sacc[9]), t5 = fmaxf(sacc[10], sacc[11]);       \
    float t6 = fmaxf(sacc[12], sacc[13]), t7 = fmaxf(sacc[14], sacc[15]);     \
    float mx = fmaxf(fmaxf(fmaxf(t0, t1), fmaxf(t2, t3)),                     \
                     fmaxf(fmaxf(t4, t5), fmaxf(t6, t7)));                    \
    mx = xhalf_max(mx);                                                       \
    float p[16];                                                              \
    _Pragma("unroll") for (int r = 0; r < 16; ++r)                            \
        p[r] = exp2f((sacc[r] - mrow) * sm);                                  \
    if (!__all((mx - mrow) * sm <= 8.0f)) { /* T13 defer-max */               \
      float mnew = fmaxf(mrow, mx);                                           \
      float rs = exp2f((mrow - mnew) * sm);                                   \
      mrow = mnew;                                                            \
      lrow *= rs;                                                             \
      _Pragma("unroll") for (int db = 0; db < 4; ++db)                        \
      _Pragma("unroll") for (int r = 0; r < 16; ++r) acc[db][r] *= rs;        \
      _Pragma("unroll") for (int r = 0; r < 16; ++r)                          \
          p[r] = exp2f((sacc[r] - mrow) * sm);                                \
    }                                                                         \
    float s0 = p[0] + p[1], s1 = p[2] + p[3], s2 = p[4] + p[5], s3 = p[6] + p[7]; \
    float s4 = p[8] + p[9], s5 = p[10] + p[11], s6 = p[12] + p[13], s7 = p[14] + p[15]; \
    float psum = ((s0 + s1) + (s2 + s3)) + ((s4 + s5) + (s6 + s7));           \
    lrow += xhalf_sum(psum);                                                  \
    u32 a0 = pktrunc(p[0], p[1]), a1 = pktrunc(p[2], p[3]);                   \
    u32 a2 = pktrunc(p[4], p[5]), a3 = pktrunc(p[6], p[7]);                   \
    u32 b0 = pktrunc(p[8], p[9]), b1 = pktrunc(p[10], p[11]);                 \
    u32 b2 = pktrunc(p[12], p[13]), b3 = pktrunc(p[14], p[15]);               \
    union { bf16x8 v; u32 u[4]; } pa0, pa1;                                   \
    xexchange(hi, a0, a1, a2, a3, pa0.u);                                     \
    xexchange(hi, b0, b1, b2, b3, pa1.u);                                     \
    __builtin_amdgcn_s_setprio(1);                                            \
    _Pragma("unroll") for (int db = 0; db < 4; ++db) {                        \
      acc[db] = __builtin_amdgcn_mfma_f32_32x32x16_bf16(vtf[0][db], pa0.v, acc[db], 0, 0, 0); \
      acc[db] = __builtin_amdgcn_mfma_f32_32x32x16_bf16(vtf[1][db], pa1.v, acc[db], 0, 0, 0); \
    }                                                                         \
    __builtin_amdgcn_s_setprio(0);                                            \
  } while (0)

#define PUBLISH(SLOT)                                                         \
  do {                                                                        \
    _Pragma("unroll") for (int db = 0; db < 4; ++db)                          \
    _Pragma("unroll") for (int rq = 0; rq < 4; ++rq) {                        \
      float4 v;                                                               \
      v.x = acc[db][rq * 4 + 0];                                              \
      v.y = acc[db][rq * 4 + 1];                                              \
      v.z = acc[db][rq * 4 + 2];                                              \
      v.w = acc[db][rq * 4 + 3];                                              \
      mO[SLOT][db * 4 + rq][l] = v;                                           \
    }                                                                         \
    mML[SLOT][0][l] = mrow;                                                   \
    mML[SLOT][1][l] = lrow;                                                   \
  } while (0)

#define MERGE(SLOT)                                                           \
  do {                                                                        \
    float m1 = mML[SLOT][0][l], l1 = mML[SLOT][1][l];                         \
    float mnew = fmaxf(mrow, m1);                                             \
    float f0 = exp2f((mrow - mnew) * sm);                                     \
    float f1 = exp2f((m1 - mnew) * sm);                                       \
    mrow = mnew;                                                              \
    lrow = lrow * f0 + l1 * f1;                                               \
    _Pragma("unroll") for (int db = 0; db < 4; ++db)                          \
    _Pragma("unroll") for (int rq = 0; rq < 4; ++rq) {                        \
      float4 o1 = mO[SLOT][db * 4 + rq][l];                                   \
      acc[db][rq * 4 + 0] = acc[db][rq * 4 + 0] * f0 + o1.x * f1;             \
      acc[db][rq * 4 + 1] = acc[db][rq * 4 + 1] * f0 + o1.y * f1;             \
      acc[db][rq * 4 + 2] = acc[db][rq * 4 + 2] * f0 + o1.z * f1;             \
      acc[db][rq * 4 + 3] = acc[db][rq * 4 + 3] * f0 + o1.w * f1;             \
    }                                                                         \
  } while (0)

  for (int phase = 0; phase < 2; ++phase) {
    const int t = phase ? (63 - x) : x;
    const int q0 = t * 32;

    bf16x8 qf[8];
    {
      const u16* qb = Q + ((size_t)(b * 2048 + q0 + ql)) * 2048 + h * 128 + hi * 8;
#pragma unroll
      for (int ck = 0; ck < 8; ++ck) qf[ck] = *(const bf16x8*)(qb + ck * 16);
    }

    f32x16 acc[4] = {};
    float mrow = -1e30f, lrow = 0.f;

    bf16x8 kfa[8], kfb[8];

    int kv0 = w * 32;
    if (kv0 <= q0) {
      LOADK(kfa, kv0);
      while (true) {
        bool more = kv0 + 128 <= q0;
        if (more) LOADK(kfb, kv0 + 128);
        COMPUTE(kfa, kv0);
        if (!more) break;
        kv0 += 128;
        more = kv0 + 128 <= q0;
        if (more) LOADK(kfa, kv0 + 128);
        COMPUTE(kfb, kv0);
        if (!more) break;
        kv0 += 128;
      }
    }

    if (w >= 2) PUBLISH(w - 2);
    __syncthreads();
    if (w < 2) MERGE(w);
    __syncthreads();
    if (w == 1) PUBLISH(0);
    __syncthreads();
    if (w == 0) {
      MERGE(0);
      float inv = 1.0f / lrow;
      u16* ob = AO + (size_t)(b * 2048 + q0 + ql) * 2048 + h * 128 + hi * 4;
#pragma unroll
      for (int db = 0; db < 4; ++db)
#pragma unroll
        for (int rq = 0; rq < 4; ++rq) {
          ushort4 o;
          o.x = f2b(acc[db][rq * 4 + 0] * inv);
          o.y = f2b(acc[db][rq * 4 + 1] * inv);
          o.z = f2b(acc[db][rq * 4 + 2] * inv);
          o.w = f2b(acc[db][rq * 4 + 3] * inv);
          *(ushort4*)(ob + db * 32 + rq * 8) = o;
        }
    }
    __syncthreads();  // slot reuse guard before next phase's PUBLISH
  }
#undef LOADK
#undef COMPUTE
#undef PUBLISH
#undef MERGE
}

// ---------------- host ----------------
extern "C" void kernel_launch(void* const* d_in, const int* in_sizes, int n_in,
                              void* d_out, int out_size, void* d_ws, size_t ws_size,
                              hipStream_t stream) {
  const float* X = (const float*)d_in[0];
  const float* Wq = (const float*)d_in[1];
  const float* Wk = (const float*)d_in[2];
  const float* Wv = (const float*)d_in[3];
  const float* Wo = (const float*)d_in[4];

  u16* ws = (u16*)d_ws;
  const size_t nX = 8388608;   // 2*2048*2048
  const size_t nWq = 4194304;  // 2048*2048
  const size_t nWk = 1048576;  // 512*2048
  u16* Xb = ws;
  u16* Wqb = Xb + nX;          // [Wq|Wk|Wv] contiguous = fused 3072x2048 weight
  u16* Wkb = Wqb + nWq;
  u16* Wvb = Wkb + nWk;
  u16* Wob = Wvb + nWk;
  u16* Qb = Wob + nWq;
  u16* Kfb = Qb + nX;          // K in fragment order (2M u16)
  u16* Vfb = Kfb + 2097152;    // V in fragment order (2M u16)
  u16* AOb = Vfb + 2097152;
  if (ws_size < (size_t)(39845888) * 2) return;

  cvt_bf16<<<2048, 256, 0, stream>>>(X, Xb, (int)nX);
  cvt_w4<<<2048, 256, 0, stream>>>(Wq, Wk, Wv, Wo, Wqb);

  // fused QKV projection (256^2 8-phase): C[4096][3072] routed to Q / K-frag / V-frag
  gemm256<3><<<dim3(12, 16), 512, 0, stream>>>(Xb, Wqb, Qb, 4096, 3072, 2048, Kfb, Vfb);

  attn_fwd<<<dim3(1024), 256, 0, stream>>>(Qb, Kfb, Vfb, AOb);

  // output projection (256^2 8-phase) -> fp32 d_out
  gemm256<2><<<dim3(8, 16), 512, 0, stream>>>(AOb, Wob, d_out, 4096, 2048, 2048, nullptr, nullptr);
}

// Round 17
// 189.730 us; speedup vs baseline: 1.2261x; 1.0441x over previous
//
#include <hip/hip_runtime.h>

typedef unsigned short u16;
typedef unsigned int u32;
typedef __attribute__((ext_vector_type(4))) float f32x4;
typedef __attribute__((ext_vector_type(16))) float f32x16;
typedef __attribute__((ext_vector_type(8))) short bf16x8;

// Problem sizes (fixed): B=2, S=2048, D=2048, NH=16, NKV=4, HD=128

__device__ __forceinline__ u16 f2b(float f) {
  u32 u = __builtin_bit_cast(u32, f);
  u = (u + 0x7fffu + ((u >> 16) & 1u)) >> 16;  // RNE
  return (u16)u;
}

__device__ __forceinline__ void gload_lds16(const void* g, void* l) {
  __builtin_amdgcn_global_load_lds((const __attribute__((address_space(1))) u32*)g,
                                   (__attribute__((address_space(3))) u32*)l, 16, 0, 0);
}

// ---- cross-half (lane <-> lane^32) exchange via v_permlane32_swap_b32 (VALU pipe) ----
#if __has_builtin(__builtin_amdgcn_permlane32_swap)
#define HAS_PLS 1
__device__ __forceinline__ void pls(u32 x, u32 y, u32& rx, u32& ry) {
  auto r = __builtin_amdgcn_permlane32_swap(x, y, false, false);
  rx = (u32)r[0];
  ry = (u32)r[1];
}
#endif

__device__ __forceinline__ float xhalf_max(float v) {
#ifdef HAS_PLS
  u32 a, b;
  pls(__builtin_bit_cast(u32, v), __builtin_bit_cast(u32, v), a, b);
  return fmaxf(__builtin_bit_cast(float, a), __builtin_bit_cast(float, b));
#else
  return fmaxf(v, __shfl_xor(v, 32));
#endif
}

__device__ __forceinline__ float xhalf_sum(float v) {
#ifdef HAS_PLS
  u32 a, b;
  pls(__builtin_bit_cast(u32, v), __builtin_bit_cast(u32, v), a, b);
  return __builtin_bit_cast(float, a) + __builtin_bit_cast(float, b);
#else
  return v + __shfl_xor(v, 32);
#endif
}

// P-fragment redistribution across lane halves
__device__ __forceinline__ void xexchange(int hi, u32 a0, u32 a1, u32 a2, u32 a3, u32* o) {
#ifdef HAS_PLS
  pls(a0, a2, o[0], o[2]);
  pls(a1, a3, o[1], o[3]);
#else
  u32 xa0 = (u32)__shfl_xor((int)a0, 32), xa1 = (u32)__shfl_xor((int)a1, 32);
  u32 xa2 = (u32)__shfl_xor((int)a2, 32), xa3 = (u32)__shfl_xor((int)a3, 32);
  o[0] = hi ? xa2 : a0;
  o[1] = hi ? xa3 : a1;
  o[2] = hi ? a2 : xa0;
  o[3] = hi ? a3 : xa1;
#endif
}

// truncating bf16 pair pack (P in [0,1]; <=2^-8 rel err, cheap: 3 ops)
__device__ __forceinline__ u32 pktrunc(float lo, float hif) {
  return (__builtin_bit_cast(u32, lo) >> 16) | (__builtin_bit_cast(u32, hif) & 0xffff0000u);
}

// ---------------- fp32 -> bf16 conversion ----------------
__global__ void cvt_bf16(const float* __restrict__ src, u16* __restrict__ dst, int n) {
  int stride = gridDim.x * blockDim.x * 4;
  for (int idx = (blockIdx.x * blockDim.x + threadIdx.x) * 4; idx < n; idx += stride) {
    float4 v = *(const float4*)(src + idx);
    ushort4 o;
    o.x = f2b(v.x); o.y = f2b(v.y); o.z = f2b(v.z); o.w = f2b(v.w);
    *(ushort4*)(dst + idx) = o;
  }
}

// fused weight conversion: dst = [Wq | Wk | Wv | Wo] contiguous
__global__ void cvt_w4(const float* __restrict__ Wq, const float* __restrict__ Wk,
                       const float* __restrict__ Wv, const float* __restrict__ Wo,
                       u16* __restrict__ dst) {
  const int total = 10485760;
  int stride = gridDim.x * blockDim.x * 4;
  for (int idx = (blockIdx.x * blockDim.x + threadIdx.x) * 4; idx < total; idx += stride) {
    const float* src;
    int off;
    if (idx < 4194304) { src = Wq; off = idx; }
    else if (idx < 5242880) { src = Wk; off = idx - 4194304; }
    else if (idx < 6291456) { src = Wv; off = idx - 5242880; }
    else { src = Wo; off = idx - 6291456; }
    float4 v = *(const float4*)(src + off);
    ushort4 o;
    o.x = f2b(v.x); o.y = f2b(v.y); o.z = f2b(v.z); o.w = f2b(v.w);
    *(ushort4*)(dst + idx) = o;
  }
}

// ---------------- 256x256 8-phase GEMM (QKV): C[M,N] = A[M,K] * B[N,K]^T ----------------
// 512 threads (8 waves, 2M x 4N), BK=64, 128 KB LDS double-buffer, T2 XOR-swizzle
// (both-sides), counted vmcnt (4 at q0 / 6 at q2), raw s_barrier, T5 setprio.
// OUT_MODE 3 = fused QKV routing (Q row-major, K/V fragment order via LDS-staged epilogue).
template<int OUT_MODE>
__global__ __launch_bounds__(512) void gemm256(const u16* __restrict__ A, const u16* __restrict__ B,
                                               void* __restrict__ Cout, int M, int N, int Kd,
                                               u16* __restrict__ Kout, u16* __restrict__ Vout) {
  __shared__ u16 smem[65536];  // 128 KB: [slot0: A 16384 | B 16384][slot1: ...]
  const int tid = threadIdx.x;
  const int l = tid & 63, w = tid >> 6;
  const int c = l & 15, g = l >> 4;
  const int wr = w >> 2, wc = w & 3;
  const int tm = blockIdx.y * 256, tn = blockIdx.x * 256;

  const int lr = tid >> 3;           // row within round
  const int lcol = (tid & 7) * 8;    // dest u16 col
  const int scol = lcol ^ (((lr >> 1) & 3) << 4);  // inverse-swizzled source col
  const int swc = ((c >> 1) & 3) << 4;             // read-side swizzle (row bits = c)

#define BARX() do { __builtin_amdgcn_s_barrier(); asm volatile("" ::: "memory"); } while (0)
#define STG(SRC, GROW0, LDS0) \
  gload_lds16((SRC) + (size_t)((GROW0) + lr) * Kd + k0n + scol, (LDS0) + lr * 64 + lcol)

  f32x4 acc[8][4] = {};

  {
    const int k0n = 0;
    u16* sAn = smem;
    u16* sBn = smem + 16384;
    STG(B, tn + 0, sBn); STG(B, tn + 64, sBn + 64 * 64);
    STG(B, tn + 128, sBn + 128 * 64); STG(B, tn + 192, sBn + 192 * 64);
    STG(A, tm + 0, sAn); STG(A, tm + 128, sAn + 128 * 64);
    STG(A, tm + 64, sAn + 64 * 64); STG(A, tm + 192, sAn + 192 * 64);
  }

  const int nt = Kd >> 6;
  for (int t = 0; t < nt; ++t) {
    const int slot = t & 1;
    u16* sAc = smem + slot * 32768;
    u16* sBc = sAc + 16384;
    u16* sAn = smem + (slot ^ 1) * 32768;
    u16* sBn = sAn + 16384;
    const int k0n = (t + 1) << 6;
    const bool st = (t + 1) < nt;

    bf16x8 bfr[4][2], af[2][2];

#define APH(q)                                                                  \
  do {                                                                          \
    _Pragma("unroll") for (int m2 = 0; m2 < 2; ++m2)                            \
    _Pragma("unroll") for (int kk = 0; kk < 2; ++kk)                            \
        af[m2][kk] = *(const bf16x8*)(sAc + (wr * 128 + (q) * 32 + m2 * 16 + c) * 64 + \
                                      ((kk * 32 + g * 8) ^ swc));               \
    __builtin_amdgcn_s_setprio(1);                                              \
    _Pragma("unroll") for (int m2 = 0; m2 < 2; ++m2)                            \
    _Pragma("unroll") for (int n = 0; n < 4; ++n)                               \
    _Pragma("unroll") for (int kk = 0; kk < 2; ++kk)                            \
        acc[(q) * 2 + m2][n] = __builtin_amdgcn_mfma_f32_16x16x32_bf16(         \
            af[m2][kk], bfr[n][kk], acc[(q) * 2 + m2][n], 0, 0, 0);             \
    __builtin_amdgcn_s_setprio(0);                                              \
  } while (0)

    // ---- q0 ----
    BARX();
    if (st) { STG(B, tn + 0, sBn); STG(B, tn + 64, sBn + 64 * 64); }
    if (st) asm volatile("s_waitcnt vmcnt(4)" ::: "memory");
    else    asm volatile("s_waitcnt vmcnt(2)" ::: "memory");
    BARX();
#pragma unroll
    for (int n = 0; n < 4; ++n)
#pragma unroll
      for (int kk = 0; kk < 2; ++kk)
        bfr[n][kk] = *(const bf16x8*)(sBc + (wc * 64 + n * 16 + c) * 64 +
                                      ((kk * 32 + g * 8) ^ swc));
    APH(0);
    // ---- q1 ----
    if (st) { STG(B, tn + 128, sBn + 128 * 64); STG(B, tn + 192, sBn + 192 * 64); }
    APH(1);
    // ---- q2 ----
    if (st) { STG(A, tm + 0, sAn); STG(A, tm + 128, sAn + 128 * 64); }
    if (st) asm volatile("s_waitcnt vmcnt(6)" ::: "memory");
    else    asm volatile("s_waitcnt vmcnt(0)" ::: "memory");
    BARX();
    APH(2);
    // ---- q3 ----
    if (st) { STG(A, tm + 64, sAn + 64 * 64); STG(A, tm + 192, sAn + 192 * 64); }
    APH(3);
#undef APH
  }

  if constexpr (OUT_MODE == 3) {
    if (tn >= 2048) {
      // ---- K/V fragment-order epilogue: scatter to 128KB LDS, then 16x8KB coalesced copy
      const bool isK = tn < 2560;
      BARX();
#pragma unroll
      for (int mi = 0; mi < 8; ++mi)
#pragma unroll
        for (int n = 0; n < 4; ++n)
#pragma unroll
          for (int i = 0; i < 4; ++i) {
            int s = wr * 128 + (mi >> 1) * 32 + (mi & 1) * 16 + g * 4 + i;  // kv row
            int e = wc * 64 + n * 16 + c;                                    // k or d col
            int chunk = (e >> 7) * 8 + (s >> 5);
            int off;
            if (isK) {
              int k = e & 127;
              off = chunk * 4096 + (k >> 4) * 512 + ((k >> 3) & 1) * 256 + (s & 31) * 8 + (k & 7);
            } else {
              int d = e & 127;
              off = chunk * 4096 + (((s >> 4) & 1) * 4 + (d >> 5)) * 512 + ((s >> 3) & 1) * 256 +
                    (d & 31) * 8 + (s & 7);
            }
            smem[off] = f2b(acc[mi][n][i]);
          }
      BARX();
      const int kvh_base = (tn - (isK ? 2048 : 2560)) >> 7;
      const int bb = tm >> 11;
      const int kvt0 = (tm & 2047) >> 5;
      u16* Out = isK ? Kout : Vout;
#pragma unroll
      for (int ch = 0; ch < 16; ++ch) {
        u16* dst = Out + (size_t)((bb * 4 + kvh_base + (ch >> 3)) * 64 + kvt0 + (ch & 7)) * 4096;
        *(bf16x8*)(dst + tid * 8) = *(const bf16x8*)(smem + ch * 4096 + tid * 8);
      }
      return;
    }
    // Q tiles: bf16 row-major, ld 2048
#pragma unroll
    for (int mi = 0; mi < 8; ++mi)
#pragma unroll
      for (int n = 0; n < 4; ++n)
#pragma unroll
        for (int i = 0; i < 4; ++i) {
          int row = tm + wr * 128 + (mi >> 1) * 32 + (mi & 1) * 16 + g * 4 + i;
          int col = tn + wc * 64 + n * 16 + c;
          ((u16*)Cout)[(size_t)row * 2048 + col] = f2b(acc[mi][n][i]);
        }
    return;
  }

  // OUT_MODE 2: fp32 row-major
#pragma unroll
  for (int mi = 0; mi < 8; ++mi)
#pragma unroll
    for (int n = 0; n < 4; ++n)
#pragma unroll
      for (int i = 0; i < 4; ++i) {
        int row = tm + wr * 128 + (mi >> 1) * 32 + (mi & 1) * 16 + g * 4 + i;
        int col = tn + wc * 64 + n * 16 + c;
        ((float*)Cout)[(size_t)row * N + col] = acc[mi][n][i];
      }
#undef STG
#undef BARX
}

// ---------------- 256x128 8-phase GEMM (O-proj): C[4096,2048] fp32 = A * B^T ----------------
// Same schedule family as gemm256, re-derived for 6 staging rounds/tile (B=2 rounds, A=4):
// issue order [B0,B64 | A0,A128 | A64,A192]; waits vmcnt(4)@q0, vmcnt(6)@q2 (tail 2/0).
// 96 KB LDS -> 1 block/CU, grid (16,16)=256 blocks = 100% CU fill (256^2 tiling left
// half the chip idle: 128 blocks). Per-wave output 128x32, acc[8][2].
__global__ __launch_bounds__(512) void gemm_op(const u16* __restrict__ A, const u16* __restrict__ B,
                                               float* __restrict__ Cout, int Kd) {
  __shared__ u16 smem[49152];  // 96 KB: [slot: A 16384 | B 8192] x 2
  const int tid = threadIdx.x;
  const int l = tid & 63, w = tid >> 6;
  const int c = l & 15, g = l >> 4;
  const int wr = w >> 2, wc = w & 3;
  const int tm = blockIdx.y * 256, tn = blockIdx.x * 128;

  const int lr = tid >> 3;
  const int lcol = (tid & 7) * 8;
  const int scol = lcol ^ (((lr >> 1) & 3) << 4);
  const int swc = ((c >> 1) & 3) << 4;

#define BARX() do { __builtin_amdgcn_s_barrier(); asm volatile("" ::: "memory"); } while (0)
#define STG(SRC, GROW0, LDS0) \
  gload_lds16((SRC) + (size_t)((GROW0) + lr) * Kd + k0n + scol, (LDS0) + lr * 64 + lcol)

  f32x4 acc[8][2] = {};

  // prologue: tile 0 -> slot 0; rounds: B0,B64, A0,A128, A64,A192
  {
    const int k0n = 0;
    u16* sAn = smem;
    u16* sBn = smem + 16384;
    STG(B, tn + 0, sBn); STG(B, tn + 64, sBn + 64 * 64);
    STG(A, tm + 0, sAn); STG(A, tm + 128, sAn + 128 * 64);
    STG(A, tm + 64, sAn + 64 * 64); STG(A, tm + 192, sAn + 192 * 64);
  }

  const int nt = Kd >> 6;
  for (int t = 0; t < nt; ++t) {
    const int slot = t & 1;
    u16* sAc = smem + slot * 24576;
    u16* sBc = sAc + 16384;
    u16* sAn = smem + (slot ^ 1) * 24576;
    u16* sBn = sAn + 16384;
    const int k0n = (t + 1) << 6;
    const bool st = (t + 1) < nt;

    bf16x8 bfr[2][2], af[2][2];

#define APH(q)                                                                  \
  do {                                                                          \
    _Pragma("unroll") for (int m2 = 0; m2 < 2; ++m2)                            \
    _Pragma("unroll") for (int kk = 0; kk < 2; ++kk)                            \
        af[m2][kk] = *(const bf16x8*)(sAc + (wr * 128 + (q) * 32 + m2 * 16 + c) * 64 + \
                                      ((kk * 32 + g * 8) ^ swc));               \
    __builtin_amdgcn_s_setprio(1);                                              \
    _Pragma("unroll") for (int m2 = 0; m2 < 2; ++m2)                            \
    _Pragma("unroll") for (int n = 0; n < 2; ++n)                               \
    _Pragma("unroll") for (int kk = 0; kk < 2; ++kk)                            \
        acc[(q) * 2 + m2][n] = __builtin_amdgcn_mfma_f32_16x16x32_bf16(         \
            af[m2][kk], bfr[n][kk], acc[(q) * 2 + m2][n], 0, 0, 0);             \
    __builtin_amdgcn_s_setprio(0);                                              \
  } while (0)

    // ---- q0 ---- (needs rounds B0,B64,A0,A128 = first 4 of this tile)
    BARX();
    if (st) { STG(B, tn + 0, sBn); STG(B, tn + 64, sBn + 64 * 64); }
    if (st) asm volatile("s_waitcnt vmcnt(4)" ::: "memory");
    else    asm volatile("s_waitcnt vmcnt(2)" ::: "memory");
    BARX();
#pragma unroll
    for (int n = 0; n < 2; ++n)
#pragma unroll
      for (int kk = 0; kk < 2; ++kk)
        bfr[n][kk] = *(const bf16x8*)(sBc + (wc * 32 + n * 16 + c) * 64 +
                                      ((kk * 32 + g * 8) ^ swc));
    APH(0);
    // ---- q1 ---- (rounds A0/A128 already published)
    if (st) { STG(A, tm + 0, sAn); STG(A, tm + 128, sAn + 128 * 64); }
    APH(1);
    // ---- q2 ---- (needs rounds A64,A192 = rounds 5,6 of this tile)
    if (st) { STG(A, tm + 64, sAn + 64 * 64); STG(A, tm + 192, sAn + 192 * 64); }
    if (st) asm volatile("s_waitcnt vmcnt(6)" ::: "memory");
    else    asm volatile("s_waitcnt vmcnt(0)" ::: "memory");
    BARX();
    APH(2);
    // ---- q3 ----
    APH(3);
#undef APH
  }

  // fp32 row-major epilogue (N = 2048)
#pragma unroll
  for (int mi = 0; mi < 8; ++mi)
#pragma unroll
    for (int n = 0; n < 2; ++n)
#pragma unroll
      for (int i = 0; i < 4; ++i) {
        int row = tm + wr * 128 + (mi >> 1) * 32 + (mi & 1) * 16 + g * 4 + i;
        int col = tn + wc * 32 + n * 16 + c;
        Cout[(size_t)row * 2048 + col] = acc[mi][n][i];
      }
#undef STG
#undef BARX
}

// ---------------- causal GQA flash attention: 32x32 swapped-operand, fully balanced ----
// grid (1024), block 256 (4 waves). XCD-affinity decode keeps each bh's K/V L2-local
// (r16: FETCH_SIZE -40%; kept as free locality). TWO phases/block: subtile x, then 63-x;
// wave w takes kv-tiles (w+4i)*32; 2-stage pairwise merge via LDS.
// K/V are MFMA-fragment-ordered: every load = 64 lanes x contiguous 16 B.
// NOTE: min-waves arg MUST be 2 — (256,4) caps VGPR at 64 and spills (round 8: 5x regression).
__global__ __launch_bounds__(256, 2) void attn_fwd(const u16* __restrict__ Q, const u16* __restrict__ Kf,
                                                   const u16* __restrict__ Vf, u16* __restrict__ AO) {
  const int l = threadIdx.x & 63, w = threadIdx.x >> 6;
  const int ql = l & 31, hi = l >> 5;
  const int id = (int)blockIdx.x;
  const int xcd = id & 7, slot = id >> 3;
  const int bh = xcd + 8 * (slot >> 5);
  const int x = slot & 31;
  const int b = bh >> 4, h = bh & 15;
  const int kvh = h >> 2;

  __shared__ float4 mO[2][16][64];
  __shared__ float mML[2][2][64];

  const float sm = 0.08838834764831845f * 1.4426950408889634f;  // 1/sqrt(128) * log2(e)

  const u16* Kfb = Kf + (size_t)(b * 4 + kvh) * 64 * 4096 + l * 8;
  const u16* Vfb = Vf + (size_t)(b * 4 + kvh) * 64 * 4096 + l * 8;

#define LOADK(KF, KV0)                                                        \
  do {                                                                        \
    const u16* kb_ = Kfb + (size_t)((KV0) >> 5) * 4096;                       \
    _Pragma("unroll") for (int ck = 0; ck < 8; ++ck)                          \
        KF[ck] = *(const bf16x8*)(kb_ + ck * 512);                            \
  } while (0)

#define COMPUTE(KF, KV0)                                                      \
  do {                                                                        \
    bf16x8 vtf[2][4];                                                         \
    {                                                                         \
      const u16* vb_ = Vfb + (size_t)((KV0) >> 5) * 4096;                     \
      _Pragma("unroll") for (int ks = 0; ks < 2; ++ks)                        \
      _Pragma("unroll") for (int db = 0; db < 4; ++db)                        \
          vtf[ks][db] = *(const bf16x8*)(vb_ + (ks * 4 + db) * 512);          \
    }                                                                         \
    f32x16 sacc = {};                                                         \
    __builtin_amdgcn_s_setprio(1);                                            \
    _Pragma("unroll") for (int ck = 0; ck < 8; ++ck)                          \
        sacc = __builtin_amdgcn_mfma_f32_32x32x16_bf16(KF[ck], qf[ck], sacc, 0, 0, 0); \
    __builtin_amdgcn_s_setprio(0);                                            \
    if ((KV0) == q0) { /* diagonal: mask kv > q */                            \
      _Pragma("unroll") for (int r = 0; r < 16; ++r) {                        \
        int crow = (r & 3) + 8 * (r >> 2) + 4 * hi;                           \
        if (crow > ql) sacc[r] = -1e30f;                                      \
      }                                                                       \
    }                                                                         \
    float t0 = fmaxf(sacc[0], sacc[1]), t1 = fmaxf(sacc[2], sacc[3]);         \
    float t2 = fmaxf(sacc[4], sacc[5]), t3 = fmaxf(sacc[6], sacc[7]);         \
    float t4 = fmaxf(sacc[8], sacc[9]), t5 = fmaxf(sacc[10], sacc[11]);       \
    float t6 = fmaxf(sacc[12], sacc[13]), t7 = fmaxf(sacc[14], sacc[15]);     \
    float mx = fmaxf(fmaxf(fmaxf(t0, t1), fmaxf(t2, t3)),                     \
                     fmaxf(fmaxf(t4, t5), fmaxf(t6, t7)));                    \
    mx = xhalf_max(mx);                                                       \
    float p[16];                                                              \
    _Pragma("unroll") for (int r = 0; r < 16; ++r)                            \
        p[r] = exp2f((sacc[r] - mrow) * sm);                                  \
    if (!__all((mx - mrow) * sm <= 8.0f)) { /* T13 defer-max */               \
      float mnew = fmaxf(mrow, mx);                                           \
      float rs = exp2f((mrow - mnew) * sm);                                   \
      mrow = mnew;                                                            \
      lrow *= rs;                                                             \
      _Pragma("unroll") for (int db = 0; db < 4; ++db)                        \
      _Pragma("unroll") for (int r = 0; r < 16; ++r) acc[db][r] *= rs;        \
      _Pragma("unroll") for (int r = 0; r < 16; ++r)                          \
          p[r] = exp2f((sacc[r] - mrow) * sm);                                \
    }                                                                         \
    float s0 = p[0] + p[1], s1 = p[2] + p[3], s2 = p[4] + p[5], s3 = p[6] + p[7]; \
    float s4 = p[8] + p[9], s5 = p[10] + p[11], s6 = p[12] + p[13], s7 = p[14] + p[15]; \
    float psum = ((s0 + s1) + (s2 + s3)) + ((s4 + s5) + (s6 + s7));           \
    lrow += xhalf_sum(psum);                                                  \
    u32 a0 = pktrunc(p[0], p[1]), a1 = pktrunc(p[2], p[3]);                   \
    u32 a2 = pktrunc(p[4], p[5]), a3 = pktrunc(p[6], p[7]);                   \
    u32 b0 = pktrunc(p[8], p[9]), b1 = pktrunc(p[10], p[11]);                 \
    u32 b2 = pktrunc(p[12], p[13]), b3 = pktrunc(p[14], p[15]);               \
    union { bf16x8 v; u32 u[4]; } pa0, pa1;                                   \
    xexchange(hi, a0, a1, a2, a3, pa0.u);                                     \
    xexchange(hi, b0, b1, b2, b3, pa1.u);                                     \
    __builtin_amdgcn_s_setprio(1);                                            \
    _Pragma("unroll") for (int db = 0; db < 4; ++db) {                        \
      acc[db] = __builtin_amdgcn_mfma_f32_32x32x16_bf16(vtf[0][db], pa0.v, acc[db], 0, 0, 0); \
      acc[db] = __builtin_amdgcn_mfma_f32_32x32x16_bf16(vtf[1][db], pa1.v, acc[db], 0, 0, 0); \
    }                                                                         \
    __builtin_amdgcn_s_setprio(0);                                            \
  } while (0)

#define PUBLISH(SLOT)                                                         \
  do {                                                                        \
    _Pragma("unroll") for (int db = 0; db < 4; ++db)                          \
    _Pragma("unroll") for (int rq = 0; rq < 4; ++rq) {                        \
      float4 v;                                                               \
      v.x = acc[db][rq * 4 + 0];                                              \
      v.y = acc[db][rq * 4 + 1];                                              \
      v.z = acc[db][rq * 4 + 2];                                              \
      v.w = acc[db][rq * 4 + 3];                                              \
      mO[SLOT][db * 4 + rq][l] = v;                                           \
    }                                                                         \
    mML[SLOT][0][l] = mrow;                                                   \
    mML[SLOT][1][l] = lrow;                                                   \
  } while (0)

#define MERGE(SLOT)                                                           \
  do {                                                                        \
    float m1 = mML[SLOT][0][l], l1 = mML[SLOT][1][l];                         \
    float mnew = fmaxf(mrow, m1);                                             \
    float f0 = exp2f((mrow - mnew) * sm);                                     \
    float f1 = exp2f((m1 - mnew) * sm);                                       \
    mrow = mnew;                                                              \
    lrow = lrow * f0 + l1 * f1;                                               \
    _Pragma("unroll") for (int db = 0; db < 4; ++db)                          \
    _Pragma("unroll") for (int rq = 0; rq < 4; ++rq) {                        \
      float4 o1 = mO[SLOT][db * 4 + rq][l];                                   \
      acc[db][rq * 4 + 0] = acc[db][rq * 4 + 0] * f0 + o1.x * f1;             \
      acc[db][rq * 4 + 1] = acc[db][rq * 4 + 1] * f0 + o1.y * f1;             \
      acc[db][rq * 4 + 2] = acc[db][rq * 4 + 2] * f0 + o1.z * f1;             \
      acc[db][rq * 4 + 3] = acc[db][rq * 4 + 3] * f0 + o1.w * f1;             \
    }                                                                         \
  } while (0)

  for (int phase = 0; phase < 2; ++phase) {
    const int t = phase ? (63 - x) : x;
    const int q0 = t * 32;

    bf16x8 qf[8];
    {
      const u16* qb = Q + ((size_t)(b * 2048 + q0 + ql)) * 2048 + h * 128 + hi * 8;
#pragma unroll
      for (int ck = 0; ck < 8; ++ck) qf[ck] = *(const bf16x8*)(qb + ck * 16);
    }

    f32x16 acc[4] = {};
    float mrow = -1e30f, lrow = 0.f;

    bf16x8 kfa[8], kfb[8];

    int kv0 = w * 32;
    if (kv0 <= q0) {
      LOADK(kfa, kv0);
      while (true) {
        bool more = kv0 + 128 <= q0;
        if (more) LOADK(kfb, kv0 + 128);
        COMPUTE(kfa, kv0);
        if (!more) break;
        kv0 += 128;
        more = kv0 + 128 <= q0;
        if (more) LOADK(kfa, kv0 + 128);
        COMPUTE(kfb, kv0);
        if (!more) break;
        kv0 += 128;
      }
    }

    if (w >= 2) PUBLISH(w - 2);
    __syncthreads();
    if (w < 2) MERGE(w);
    __syncthreads();
    if (w == 1) PUBLISH(0);
    __syncthreads();
    if (w == 0) {
      MERGE(0);
      float inv = 1.0f / lrow;
      u16* ob = AO + (size_t)(b * 2048 + q0 + ql) * 2048 + h * 128 + hi * 4;
#pragma unroll
      for (int db = 0; db < 4; ++db)
#pragma unroll
        for (int rq = 0; rq < 4; ++rq) {
          ushort4 o;
          o.x = f2b(acc[db][rq * 4 + 0] * inv);
          o.y = f2b(acc[db][rq * 4 + 1] * inv);
          o.z = f2b(acc[db][rq * 4 + 2] * inv);
          o.w = f2b(acc[db][rq * 4 + 3] * inv);
          *(ushort4*)(ob + db * 32 + rq * 8) = o;
        }
    }
    __syncthreads();  // slot reuse guard before next phase's PUBLISH
  }
#undef LOADK
#undef COMPUTE
#undef PUBLISH
#undef MERGE
}

// ---------------- host ----------------
extern "C" void kernel_launch(void* const* d_in, const int* in_sizes, int n_in,
                              void* d_out, int out_size, void* d_ws, size_t ws_size,
                              hipStream_t stream) {
  const float* X = (const float*)d_in[0];
  const float* Wq = (const float*)d_in[1];
  const float* Wk = (const float*)d_in[2];
  const float* Wv = (const float*)d_in[3];
  const float* Wo = (const float*)d_in[4];

  u16* ws = (u16*)d_ws;
  const size_t nX = 8388608;   // 2*2048*2048
  const size_t nWq = 4194304;  // 2048*2048
  const size_t nWk = 1048576;  // 512*2048
  u16* Xb = ws;
  u16* Wqb = Xb + nX;          // [Wq|Wk|Wv] contiguous = fused 3072x2048 weight
  u16* Wkb = Wqb + nWq;
  u16* Wvb = Wkb + nWk;
  u16* Wob = Wvb + nWk;
  u16* Qb = Wob + nWq;
  u16* Kfb = Qb + nX;          // K in fragment order (2M u16)
  u16* Vfb = Kfb + 2097152;    // V in fragment order (2M u16)
  u16* AOb = Vfb + 2097152;
  if (ws_size < (size_t)(39845888) * 2) return;

  cvt_bf16<<<2048, 256, 0, stream>>>(X, Xb, (int)nX);
  cvt_w4<<<2048, 256, 0, stream>>>(Wq, Wk, Wv, Wo, Wqb);

  // fused QKV projection (256^2 8-phase): C[4096][3072] routed to Q / K-frag / V-frag
  gemm256<3><<<dim3(12, 16), 512, 0, stream>>>(Xb, Wqb, Qb, 4096, 3072, 2048, Kfb, Vfb);

  attn_fwd<<<dim3(1024), 256, 0, stream>>>(Qb, Kfb, Vfb, AOb);

  // output projection (256x128 8-phase, 256 blocks = full chip) -> fp32 d_out
  gemm_op<<<dim3(16, 16), 512, 0, stream>>>(AOb, Wob, (float*)d_out, 2048);
}